// Round 12
// baseline (2470.833 us; speedup 1.0000x reference)
//
#include <hip/hip_runtime.h>
#include <hip/hip_bf16.h>

#define B_ 4
#define L_ 4096
#define C_ 2048
#define NH_ 32
#define K_ 16
#define F_ 64
#define NC_ 256
#define EPS_ 1e-6f

typedef _Float16 half8 __attribute__((ext_vector_type(8)));
typedef _Float16 half4 __attribute__((ext_vector_type(4)));
typedef float f32x4 __attribute__((ext_vector_type(4)));

// sum over 16-lane group via DPP (VALU pipe, no LDS): xor1, xor2, ror4, ror8
__device__ __forceinline__ float red16(float v) {
  int x;
  x = __builtin_amdgcn_update_dpp(0, __builtin_bit_cast(int, v), 0xB1, 0xF, 0xF, true);
  v += __builtin_bit_cast(float, x);
  x = __builtin_amdgcn_update_dpp(0, __builtin_bit_cast(int, v), 0x4E, 0xF, 0xF, true);
  v += __builtin_bit_cast(float, x);
  x = __builtin_amdgcn_update_dpp(0, __builtin_bit_cast(int, v), 0x124, 0xF, 0xF, true);
  v += __builtin_bit_cast(float, x);
  x = __builtin_amdgcn_update_dpp(0, __builtin_bit_cast(int, v), 0x128, 0xF, 0xF, true);
  v += __builtin_bit_cast(float, x);
  return v;
}

__device__ __forceinline__ void gl_lds16(const _Float16* g, _Float16* l) {
  __builtin_amdgcn_global_load_lds(
      (const __attribute__((address_space(1))) void*)g,
      (__attribute__((address_space(3))) void*)l, 16, 0, 0);
}

// ---------------- cast fp32 -> f16, 8 elems/thread ----------------
__global__ __launch_bounds__(256) void cast_f16(const float* __restrict__ in,
                                                _Float16* __restrict__ out, int n8) {
  int i = blockIdx.x * 256 + threadIdx.x;
  if (i >= n8) return;
  const float4* ip = (const float4*)in;
  float4 a = ip[2*i], b = ip[2*i+1];
  half8 o;
  o[0]=(_Float16)a.x; o[1]=(_Float16)a.y; o[2]=(_Float16)a.z; o[3]=(_Float16)a.w;
  o[4]=(_Float16)b.x; o[5]=(_Float16)b.y; o[6]=(_Float16)b.z; o[7]=(_Float16)b.w;
  ((half8*)out)[i] = o;
}

// ---------------- f16 MFMA GEMM (m97 structure) ----------------
#define TM 128
#define TN 128
#define TK 32

template<typename OT>
__global__ __launch_bounds__(256) void gemm_f16(
    const _Float16* __restrict__ A, const _Float16* __restrict__ Bm,
    OT* __restrict__ C, int M, int N, int Kd)
{
  __shared__ __align__(16) _Float16 As[TM*TK];
  __shared__ __align__(16) _Float16 Bs[TN*TK];
  const int t = threadIdx.x;
  const int lane = t & 63;
  const int bn = blockIdx.x, bm = blockIdx.y;
  const int w = t >> 6;
  const int wm = (w >> 1) * 64, wn = (w & 1) * 64;

  const _Float16* ga1 = A  + ((long)(bm*TM +      (t>>2)))*Kd + (t&3)*8;
  const _Float16* ga2 = A  + ((long)(bm*TM + 64 + (t>>2)))*Kd + (t&3)*8;
  const _Float16* gb1 = Bm + ((long)(bn*TN +      (t>>2)))*Kd + (t&3)*8;
  const _Float16* gb2 = Bm + ((long)(bn*TN + 64 + (t>>2)))*Kd + (t&3)*8;
  _Float16* la1 = As + (size_t)t*8;
  _Float16* la2 = As + (size_t)(t+256)*8;
  _Float16* lb1 = Bs + (size_t)t*8;
  _Float16* lb2 = Bs + (size_t)(t+256)*8;

  f32x4 acc[4][4];
#pragma unroll
  for (int i = 0; i < 4; ++i)
#pragma unroll
    for (int j = 0; j < 4; ++j) acc[i][j] = (f32x4){0.f,0.f,0.f,0.f};

  for (int k0 = 0; k0 < Kd; k0 += TK) {
    __syncthreads();
    gl_lds16(ga1 + k0, la1);
    gl_lds16(ga2 + k0, la2);
    gl_lds16(gb1 + k0, lb1);
    gl_lds16(gb2 + k0, lb2);
    __syncthreads();
    half8 af[4], bf[4];
#pragma unroll
    for (int i = 0; i < 4; ++i)
      af[i] = *(const half8*)(As + (size_t)(wm + i*16 + (lane&15))*TK + (lane>>4)*8);
#pragma unroll
    for (int j = 0; j < 4; ++j)
      bf[j] = *(const half8*)(Bs + (size_t)(wn + j*16 + (lane&15))*TK + (lane>>4)*8);
#pragma unroll
    for (int i = 0; i < 4; ++i)
#pragma unroll
      for (int j = 0; j < 4; ++j)
        acc[i][j] = __builtin_amdgcn_mfma_f32_16x16x32_f16(af[i], bf[j], acc[i][j], 0, 0, 0);
  }

  const int cr = (lane >> 4) * 4, cc = lane & 15;
#pragma unroll
  for (int i = 0; i < 4; ++i)
#pragma unroll
    for (int j = 0; j < 4; ++j)
#pragma unroll
      for (int r = 0; r < 4; ++r) {
        long row = (long)bm*TM + wm + i*16 + cr + r;
        long col = (long)bn*TN + wn + j*16 + cc;
        C[row*(long)N + col] = (OT)acc[i][j][r];
      }
}

// ---------------- ilr / coeff (fp32) ----------------
__global__ __launch_bounds__(256) void ilr_kernel(
    const float* __restrict__ hid, const float* __restrict__ lin_w,
    const float* __restrict__ lin_b, float* __restrict__ coeff)
{
  const int t = threadIdx.x;
  const int lane = t & 63;
  const int w = t >> 6;
  const int row0 = blockIdx.x * 16 + w * 4;

  float4 hv[4][8];
#pragma unroll
  for (int r = 0; r < 4; ++r) {
    const float* hp = hid + (size_t)(row0 + r) * C_;
#pragma unroll
    for (int i = 0; i < 8; ++i) hv[r][i] = *(const float4*)(hp + i*256 + lane*4);
  }
  float res[4] = {0.f,0.f,0.f,0.f};
  for (int h = 0; h < NH_; ++h) {
    const float* wp = lin_w + (size_t)h * C_;
    float s[4] = {0.f,0.f,0.f,0.f};
#pragma unroll
    for (int i = 0; i < 8; ++i) {
      float4 wv = *(const float4*)(wp + i*256 + lane*4);
#pragma unroll
      for (int r = 0; r < 4; ++r)
        s[r] += hv[r][i].x*wv.x + hv[r][i].y*wv.y + hv[r][i].z*wv.z + hv[r][i].w*wv.w;
    }
#pragma unroll
    for (int o = 32; o > 0; o >>= 1)
#pragma unroll
      for (int r = 0; r < 4; ++r) s[r] += __shfl_xor(s[r], o, 64);
    if (lane == h) { res[0]=s[0]; res[1]=s[1]; res[2]=s[2]; res[3]=s[3]; }
  }
  if (lane < NH_) {
    float lb = lin_b[lane];
#pragma unroll
    for (int r = 0; r < 4; ++r) {
      int row = row0 + r;
      int b = row >> 12;
      int li = row & (L_ - 1);
      int k = li & (K_ - 1);
      float x = res[r] + lb;
      float sp = (x > 20.f) ? x : log1pf(expf(x));
      float v = (1.0f / (float)(k + 1)) * sp * (1.0f / (float)F_);
      coeff[((size_t)(b * NH_ + lane)) * L_ + li] = v;
    }
  }
}

// ---------------- TTT scan v7: 1 wave, TWO heads interleaved ----------------
// Two independent (b,h) chains per wave; every phase unrolled over hh so the
// scheduler fills one chain's latency bubbles with the other's instructions.
// W1 = Whi (f16, fixed) + Wlo16 (f16 residual, updated in place each chunk).
// Layouts (16x16x16 MFMA, q=lane>>4, ln=lane&15):
//   A-frag: A[ln][4q+j];  B-frag: B[4q+j][ln];  C/D: C[4q+r][ln] (== B-frag).
// Identity-transpose: (M@I) relays A-frag of M into C/D positions.

struct Ck {
  half4 xbA[4], xcA[4], xaA[4];  // A-frags per feature-tile
  float co4[4], co15;
};

__device__ __forceinline__ void load_ck(
    Ck& c, const _Float16* Q, const _Float16* Kp, const _Float16* V,
    const float* co, size_t rowbase, int hoff, size_t cobase, int n, int q, int ln)
{
#pragma unroll
  for (int kt = 0; kt < 4; ++kt) {
    size_t idx = (rowbase + ln) * C_ + hoff + 16*kt + 4*q;
    c.xbA[kt] = *(const half4*)(Kp + idx);
    c.xcA[kt] = *(const half4*)(Q  + idx);
    c.xaA[kt] = *(const half4*)(V  + idx);
  }
#pragma unroll
  for (int r = 0; r < 4; ++r) c.co4[r] = co[cobase + (size_t)n*K_ + 4*q + r];
  c.co15 = co[cobase + (size_t)n*K_ + 15];
}

__global__ __launch_bounds__(64, 1) void scan_kernel(
    const _Float16* __restrict__ Q, const _Float16* __restrict__ Kp,
    const _Float16* __restrict__ V,
    const float* __restrict__ coeff, const float* __restrict__ W1g, const float* __restrict__ b1g,
    const float* __restrict__ ln_w, const float* __restrict__ ln_b,
    _Float16* __restrict__ OF)
{
  const int bh0 = blockIdx.x * 2;            // even; bh0 and bh0+1 share b
  const int b = bh0 >> 5;
  const int lane = threadIdx.x;
  const int q = lane >> 4, ln = lane & 15;
  const int hoffA[2]    = {(bh0 & 31) * F_, ((bh0 & 31) + 1) * F_};
  const size_t cobaseA[2] = {(size_t)bh0 * L_, (size_t)(bh0 + 1) * L_};
  const size_t brow = (size_t)b * L_;

  // persistent W1 state per head: f16 hi (fixed) + f16 residual (updated)
  half4 Whi[2][4][4], Wlo16[2][4][4];
#pragma unroll
  for (int hh = 0; hh < 2; ++hh)
#pragma unroll
    for (int kt = 0; kt < 4; ++kt)
#pragma unroll
      for (int t = 0; t < 4; ++t) {
        half4 hv, lv;
#pragma unroll
        for (int j = 0; j < 4; ++j) {
          float wv = W1g[(size_t)((bh0 & 31) + hh)*F_*F_ + (size_t)(16*kt + 4*q + j)*F_ + 16*t + ln];
          _Float16 hi = (_Float16)wv;
          hv[j] = hi; lv[j] = (_Float16)(wv - (float)hi);
        }
        Whi[hh][kt][t] = hv; Wlo16[hh][kt][t] = lv;
      }
  float b1r[2][4], gamt[2][4], bett[2][4];
#pragma unroll
  for (int hh = 0; hh < 2; ++hh)
#pragma unroll
    for (int t = 0; t < 4; ++t) {
      b1r[hh][t]  = b1g[hoffA[hh] + 16*t + ln];
      gamt[hh][t] = ln_w[hoffA[hh] + 16*t + ln];
      bett[hh][t] = ln_b[hoffA[hh] + 16*t + ln];
    }
  half4 maskA, maskI;
#pragma unroll
  for (int j = 0; j < 4; ++j) {
    maskA[j] = (_Float16)((4*q + j <= ln) ? 1.f : 0.f);
    maskI[j] = (_Float16)((4*q + j == ln) ? 1.f : 0.f);
  }
  const f32x4 zf4 = (f32x4){0.f, 0.f, 0.f, 0.f};

  auto body2 = [&](const Ck* ck, int n) {   // ck[2], one per head
    const size_t rowbase = brow + (size_t)n * K_;

    // 0. identity-transposes: tg=(xa-xb), xcs, xbT into C/D positions
    f32x4 tgD[2][4], xcsD[2][4];
    half4 xbT[2][4];
#pragma unroll
    for (int hh = 0; hh < 2; ++hh)
#pragma unroll
      for (int t = 0; t < 4; ++t) {
        half4 dd = ck[hh].xaA[t] - ck[hh].xbA[t];
        tgD[hh][t]  = __builtin_amdgcn_mfma_f32_16x16x16f16(dd, maskI, zf4, 0, 0, 0);
        xcsD[hh][t] = __builtin_amdgcn_mfma_f32_16x16x16f16(ck[hh].xcA[t], maskI, zf4, 0, 0, 0);
        f32x4 x = __builtin_amdgcn_mfma_f32_16x16x16f16(ck[hh].xbA[t], maskI, zf4, 0, 0, 0);
        half4 v;
#pragma unroll
        for (int r = 0; r < 4; ++r) v[r] = (_Float16)x[r];
        xbT[hh][t] = v;
      }

    // 1. z = xb@W1 + b1 (hi/lo chains split)
    f32x4 za[2][4];
#pragma unroll
    for (int hh = 0; hh < 2; ++hh)
#pragma unroll
      for (int t = 0; t < 4; ++t) {
        f32x4 zh = (f32x4){b1r[hh][t], b1r[hh][t], b1r[hh][t], b1r[hh][t]};
        f32x4 zl = zf4;
#pragma unroll
        for (int kt = 0; kt < 4; ++kt) {
          zh = __builtin_amdgcn_mfma_f32_16x16x16f16(ck[hh].xbA[kt], Whi[hh][kt][t],   zh, 0, 0, 0);
          zl = __builtin_amdgcn_mfma_f32_16x16x16f16(ck[hh].xbA[kt], Wlo16[hh][kt][t], zl, 0, 0, 0);
        }
        za[hh][t] = zh + zl;
      }

    // 2. attnT = xb@xc^T (2+2 split), masked -> f16 A-frag of attn
    half4 atf[2];
#pragma unroll
    for (int hh = 0; hh < 2; ++hh) {
      f32x4 at0 = zf4, at1 = zf4;
      at0 = __builtin_amdgcn_mfma_f32_16x16x16f16(ck[hh].xbA[0], ck[hh].xcA[0], at0, 0, 0, 0);
      at0 = __builtin_amdgcn_mfma_f32_16x16x16f16(ck[hh].xbA[1], ck[hh].xcA[1], at0, 0, 0, 0);
      at1 = __builtin_amdgcn_mfma_f32_16x16x16f16(ck[hh].xbA[2], ck[hh].xcA[2], at1, 0, 0, 0);
      at1 = __builtin_amdgcn_mfma_f32_16x16x16f16(ck[hh].xbA[3], ck[hh].xcA[3], at1, 0, 0, 0);
      f32x4 at = at0 + at1;
#pragma unroll
      for (int r = 0; r < 4; ++r) atf[hh][r] = (_Float16)((4*q + r <= ln) ? at[r] : 0.f);
    }

    // 3. LN-L2 backward -> gZ
    half4 gzf[2][4];
#pragma unroll
    for (int hh = 0; hh < 2; ++hh)
#pragma unroll
      for (int r = 0; r < 4; ++r) {
        float zr[4], s1 = 0.f, s2 = 0.f;
#pragma unroll
        for (int t = 0; t < 4; ++t) { zr[t] = za[hh][t][r]; s1 += zr[t]; s2 += zr[t]*zr[t]; }
        s1 = red16(s1); s2 = red16(s2);
        float mu = s1 * (1.f/F_);
        float istd = rsqrtf(s2 * (1.f/F_) - mu*mu + EPS_);
        float xh[4], gy[4], sg = 0.f, sx = 0.f;
#pragma unroll
        for (int t = 0; t < 4; ++t) {
          xh[t] = (zr[t] - mu) * istd;
          gy[t] = (gamt[hh][t]*xh[t] + bett[hh][t] - tgD[hh][t][r]) * gamt[hh][t];
          sg += gy[t]; sx += gy[t]*xh[t];
        }
        sg = red16(sg); sx = red16(sx);
        const float sc = istd * (1.f/F_);
#pragma unroll
        for (int t = 0; t < 4; ++t)
          gzf[hh][t][r] = (_Float16)((F_*gy[t] - sg - xh[t]*sx) * sc);
      }

    // 4. cum = maskL@gZ ; ag = attn@gZ
    f32x4 cum[2][4], ag[2][4];
#pragma unroll
    for (int hh = 0; hh < 2; ++hh)
#pragma unroll
      for (int t = 0; t < 4; ++t) {
        cum[hh][t] = __builtin_amdgcn_mfma_f32_16x16x16f16(maskA, gzf[hh][t], zf4, 0, 0, 0);
        ag[hh][t]  = __builtin_amdgcn_mfma_f32_16x16x16f16(atf[hh], gzf[hh][t], zf4, 0, 0, 0);
      }

    // 5. zb = xc@W1 + b1 - co*(ag + cum)
    float zbf[2][4][4];
#pragma unroll
    for (int hh = 0; hh < 2; ++hh)
#pragma unroll
      for (int t = 0; t < 4; ++t) {
        f32x4 zh = zf4, zl = zf4;
#pragma unroll
        for (int kt = 0; kt < 4; ++kt) {
          zh = __builtin_amdgcn_mfma_f32_16x16x16f16(ck[hh].xcA[kt], Whi[hh][kt][t],   zh, 0, 0, 0);
          zl = __builtin_amdgcn_mfma_f32_16x16x16f16(ck[hh].xcA[kt], Wlo16[hh][kt][t], zl, 0, 0, 0);
        }
        f32x4 s = zh + zl;
#pragma unroll
        for (int r = 0; r < 4; ++r)
          zbf[hh][t][r] = s[r] + b1r[hh][t] - ck[hh].co4[r]*(ag[hh][t][r] + cum[hh][t][r]);
      }

    // 6. out = xc + LN(zb), scalar f16 stores
#pragma unroll
    for (int hh = 0; hh < 2; ++hh)
#pragma unroll
      for (int r = 0; r < 4; ++r) {
        float zr[4], s1 = 0.f, s2 = 0.f;
#pragma unroll
        for (int t = 0; t < 4; ++t) { zr[t] = zbf[hh][t][r]; s1 += zr[t]; s2 += zr[t]*zr[t]; }
        s1 = red16(s1); s2 = red16(s2);
        float mu = s1 * (1.f/F_);
        float istd = rsqrtf(s2 * (1.f/F_) - mu*mu + EPS_);
#pragma unroll
        for (int t = 0; t < 4; ++t) {
          float ov = xcsD[hh][t][r] + gamt[hh][t]*((zr[t] - mu)*istd) + bett[hh][t];
          OF[(rowbase + 4*q + r) * C_ + hoffA[hh] + 16*t + ln] = (_Float16)ov;
        }
      }

    // 7. b1 <- row 15 of b1_bar (lanes q==3, reg r=3)
#pragma unroll
    for (int hh = 0; hh < 2; ++hh)
#pragma unroll
      for (int t = 0; t < 4; ++t) {
        float tmp = b1r[hh][t] - ck[hh].co15 * cum[hh][t][3];
        b1r[hh][t] = __shfl(tmp, 48 + ln, 64);
      }

    // 8. W1 residual update: Wlo16 -= f16(co15 * xb^T@gZ)
#pragma unroll
    for (int hh = 0; hh < 2; ++hh)
#pragma unroll
      for (int mt = 0; mt < 4; ++mt)
#pragma unroll
        for (int t = 0; t < 4; ++t) {
          f32x4 d = __builtin_amdgcn_mfma_f32_16x16x16f16(xbT[hh][mt], gzf[hh][t], zf4, 0, 0, 0);
          half4 dt;
#pragma unroll
          for (int r = 0; r < 4; ++r) dt[r] = (_Float16)(ck[hh].co15 * d[r]);
          Wlo16[hh][mt][t] = Wlo16[hh][mt][t] - dt;
        }
  };

  Ck cka[2], ckb[2];
#pragma unroll
  for (int hh = 0; hh < 2; ++hh)
    load_ck(cka[hh], Q, Kp, V, coeff, brow, hoffA[hh], cobaseA[hh], 0, q, ln);
  for (int n = 0; n < NC_; n += 2) {
#pragma unroll
    for (int hh = 0; hh < 2; ++hh)
      load_ck(ckb[hh], Q, Kp, V, coeff, brow + (size_t)(n+1)*K_, hoffA[hh], cobaseA[hh], n+1, q, ln);
    body2(cka, n);
    int np = (n + 2 < NC_) ? n + 2 : NC_ - 1;
#pragma unroll
    for (int hh = 0; hh < 2; ++hh)
      load_ck(cka[hh], Q, Kp, V, coeff, brow + (size_t)np*K_, hoffA[hh], cobaseA[hh], np, q, ln);
    body2(ckb, n + 1);
  }
}

extern "C" void kernel_launch(void* const* d_in, const int* in_sizes, int n_in,
                              void* d_out, int out_size, void* d_ws, size_t ws_size,
                              hipStream_t stream)
{
  const float* hid   = (const float*)d_in[0];
  const float* q_w   = (const float*)d_in[1];
  const float* k_w   = (const float*)d_in[2];
  const float* v_w   = (const float*)d_in[3];
  const float* o_w   = (const float*)d_in[4];
  const float* lin_w = (const float*)d_in[5];
  const float* lin_b = (const float*)d_in[6];
  const float* ln_w  = (const float*)d_in[7];
  const float* ln_b  = (const float*)d_in[8];
  const float* W1    = (const float*)d_in[9];
  const float* b1    = (const float*)d_in[10];
  float* out = (float*)d_out;

  const size_t BLC = (size_t)B_ * L_ * C_;
  const size_t CC  = (size_t)C_ * C_;
  _Float16* HF = (_Float16*)d_ws;               // hid f16; later scan output
  _Float16* WF = HF + BLC;
  _Float16* KF = WF + CC;
  _Float16* VF = KF + BLC;
  float*    CO = (float*)(VF + BLC);
  _Float16* QF = (_Float16*)d_out;              // Q f16 in d_out (dead before final GEMM)

  const int M = B_ * L_, N = C_, Kd = C_;
  dim3 gg(N / TN, M / TM);
  const int n8h = (int)(BLC / 8);
  const int n8w = (int)(CC / 8);

  cast_f16<<<(n8h+255)/256, 256, 0, stream>>>(hid, HF, n8h);
  cast_f16<<<(n8w+255)/256, 256, 0, stream>>>(q_w, WF, n8w);
  gemm_f16<_Float16><<<gg, 256, 0, stream>>>(HF, WF, QF, M, N, Kd);
  cast_f16<<<(n8w+255)/256, 256, 0, stream>>>(k_w, WF, n8w);
  gemm_f16<_Float16><<<gg, 256, 0, stream>>>(HF, WF, KF, M, N, Kd);
  cast_f16<<<(n8w+255)/256, 256, 0, stream>>>(v_w, WF, n8w);
  gemm_f16<_Float16><<<gg, 256, 0, stream>>>(HF, WF, VF, M, N, Kd);
  ilr_kernel<<<M / 16, 256, 0, stream>>>(hid, lin_w, lin_b, CO);
  scan_kernel<<<B_ * NH_ / 2, 64, 0, stream>>>(QF, KF, VF, CO, W1, b1, ln_w, ln_b, HF);
  cast_f16<<<(n8w+255)/256, 256, 0, stream>>>(o_w, WF, n8w);
  gemm_f16<float><<<gg, 256, 0, stream>>>(HF, WF, out, M, N, Kd);
}

// Round 13
// 1413.739 us; speedup vs baseline: 1.7477x; 1.7477x over previous
//
#include <hip/hip_runtime.h>
#include <hip/hip_bf16.h>

#define B_ 4
#define L_ 4096
#define C_ 2048
#define NH_ 32
#define K_ 16
#define F_ 64
#define NC_ 256
#define EPS_ 1e-6f

typedef _Float16 half8 __attribute__((ext_vector_type(8)));
typedef _Float16 half4 __attribute__((ext_vector_type(4)));
typedef float f32x4 __attribute__((ext_vector_type(4)));

// sum over 16-lane group via DPP (VALU pipe, no LDS): xor1, xor2, ror4, ror8
__device__ __forceinline__ float red16(float v) {
  int x;
  x = __builtin_amdgcn_update_dpp(0, __builtin_bit_cast(int, v), 0xB1, 0xF, 0xF, true);
  v += __builtin_bit_cast(float, x);
  x = __builtin_amdgcn_update_dpp(0, __builtin_bit_cast(int, v), 0x4E, 0xF, 0xF, true);
  v += __builtin_bit_cast(float, x);
  x = __builtin_amdgcn_update_dpp(0, __builtin_bit_cast(int, v), 0x124, 0xF, 0xF, true);
  v += __builtin_bit_cast(float, x);
  x = __builtin_amdgcn_update_dpp(0, __builtin_bit_cast(int, v), 0x128, 0xF, 0xF, true);
  v += __builtin_bit_cast(float, x);
  return v;
}

__device__ __forceinline__ void gl_lds16(const _Float16* g, _Float16* l) {
  __builtin_amdgcn_global_load_lds(
      (const __attribute__((address_space(1))) void*)g,
      (__attribute__((address_space(3))) void*)l, 16, 0, 0);
}

// ---------------- cast fp32 -> f16, 8 elems/thread ----------------
__global__ __launch_bounds__(256) void cast_f16(const float* __restrict__ in,
                                                _Float16* __restrict__ out, int n8) {
  int i = blockIdx.x * 256 + threadIdx.x;
  if (i >= n8) return;
  const float4* ip = (const float4*)in;
  float4 a = ip[2*i], b = ip[2*i+1];
  half8 o;
  o[0]=(_Float16)a.x; o[1]=(_Float16)a.y; o[2]=(_Float16)a.z; o[3]=(_Float16)a.w;
  o[4]=(_Float16)b.x; o[5]=(_Float16)b.y; o[6]=(_Float16)b.z; o[7]=(_Float16)b.w;
  ((half8*)out)[i] = o;
}

// ---------------- f16 MFMA GEMM (m97 structure) ----------------
#define TM 128
#define TN 128
#define TK 32

template<typename OT>
__global__ __launch_bounds__(256) void gemm_f16(
    const _Float16* __restrict__ A, const _Float16* __restrict__ Bm,
    OT* __restrict__ C, int M, int N, int Kd)
{
  __shared__ __align__(16) _Float16 As[TM*TK];
  __shared__ __align__(16) _Float16 Bs[TN*TK];
  const int t = threadIdx.x;
  const int lane = t & 63;
  const int bn = blockIdx.x, bm = blockIdx.y;
  const int w = t >> 6;
  const int wm = (w >> 1) * 64, wn = (w & 1) * 64;

  const _Float16* ga1 = A  + ((long)(bm*TM +      (t>>2)))*Kd + (t&3)*8;
  const _Float16* ga2 = A  + ((long)(bm*TM + 64 + (t>>2)))*Kd + (t&3)*8;
  const _Float16* gb1 = Bm + ((long)(bn*TN +      (t>>2)))*Kd + (t&3)*8;
  const _Float16* gb2 = Bm + ((long)(bn*TN + 64 + (t>>2)))*Kd + (t&3)*8;
  _Float16* la1 = As + (size_t)t*8;
  _Float16* la2 = As + (size_t)(t+256)*8;
  _Float16* lb1 = Bs + (size_t)t*8;
  _Float16* lb2 = Bs + (size_t)(t+256)*8;

  f32x4 acc[4][4];
#pragma unroll
  for (int i = 0; i < 4; ++i)
#pragma unroll
    for (int j = 0; j < 4; ++j) acc[i][j] = (f32x4){0.f,0.f,0.f,0.f};

  for (int k0 = 0; k0 < Kd; k0 += TK) {
    __syncthreads();
    gl_lds16(ga1 + k0, la1);
    gl_lds16(ga2 + k0, la2);
    gl_lds16(gb1 + k0, lb1);
    gl_lds16(gb2 + k0, lb2);
    __syncthreads();
    half8 af[4], bf[4];
#pragma unroll
    for (int i = 0; i < 4; ++i)
      af[i] = *(const half8*)(As + (size_t)(wm + i*16 + (lane&15))*TK + (lane>>4)*8);
#pragma unroll
    for (int j = 0; j < 4; ++j)
      bf[j] = *(const half8*)(Bs + (size_t)(wn + j*16 + (lane&15))*TK + (lane>>4)*8);
#pragma unroll
    for (int i = 0; i < 4; ++i)
#pragma unroll
      for (int j = 0; j < 4; ++j)
        acc[i][j] = __builtin_amdgcn_mfma_f32_16x16x32_f16(af[i], bf[j], acc[i][j], 0, 0, 0);
  }

  const int cr = (lane >> 4) * 4, cc = lane & 15;
#pragma unroll
  for (int i = 0; i < 4; ++i)
#pragma unroll
    for (int j = 0; j < 4; ++j)
#pragma unroll
      for (int r = 0; r < 4; ++r) {
        long row = (long)bm*TM + wm + i*16 + cr + r;
        long col = (long)bn*TN + wn + j*16 + cc;
        C[row*(long)N + col] = (OT)acc[i][j][r];
      }
}

// ---------------- ilr / coeff (fp32) ----------------
__global__ __launch_bounds__(256) void ilr_kernel(
    const float* __restrict__ hid, const float* __restrict__ lin_w,
    const float* __restrict__ lin_b, float* __restrict__ coeff)
{
  const int t = threadIdx.x;
  const int lane = t & 63;
  const int w = t >> 6;
  const int row0 = blockIdx.x * 16 + w * 4;

  float4 hv[4][8];
#pragma unroll
  for (int r = 0; r < 4; ++r) {
    const float* hp = hid + (size_t)(row0 + r) * C_;
#pragma unroll
    for (int i = 0; i < 8; ++i) hv[r][i] = *(const float4*)(hp + i*256 + lane*4);
  }
  float res[4] = {0.f,0.f,0.f,0.f};
  for (int h = 0; h < NH_; ++h) {
    const float* wp = lin_w + (size_t)h * C_;
    float s[4] = {0.f,0.f,0.f,0.f};
#pragma unroll
    for (int i = 0; i < 8; ++i) {
      float4 wv = *(const float4*)(wp + i*256 + lane*4);
#pragma unroll
      for (int r = 0; r < 4; ++r)
        s[r] += hv[r][i].x*wv.x + hv[r][i].y*wv.y + hv[r][i].z*wv.z + hv[r][i].w*wv.w;
    }
#pragma unroll
    for (int o = 32; o > 0; o >>= 1)
#pragma unroll
      for (int r = 0; r < 4; ++r) s[r] += __shfl_xor(s[r], o, 64);
    if (lane == h) { res[0]=s[0]; res[1]=s[1]; res[2]=s[2]; res[3]=s[3]; }
  }
  if (lane < NH_) {
    float lb = lin_b[lane];
#pragma unroll
    for (int r = 0; r < 4; ++r) {
      int row = row0 + r;
      int b = row >> 12;
      int li = row & (L_ - 1);
      int k = li & (K_ - 1);
      float x = res[r] + lb;
      float sp = (x > 20.f) ? x : log1pf(expf(x));
      float v = (1.0f / (float)(k + 1)) * sp * (1.0f / (float)F_);
      coeff[((size_t)(b * NH_ + lane)) * L_ + li] = v;
    }
  }
}

// ---------------- TTT scan v8: v6 2-wave pipeline, single-f16 W1 ----------
// wave0 (producer): za = xb@W1+b1 -> LN-L2 -> gZ, publishes gZ via LDS.
// wave1 (consumer): one chunk behind: attnT, cum/ag, zb, LN, out-store.
// BOTH waves maintain bit-identical f16 W1 replicas (same f16 delta from the
// same f16 gZ -> deterministic). gZ handoff: 4-slot rotating LDS buffer, one
// __syncthreads per chunk (reader's slot rewritten >= 2 barriers later).
// Layouts (16x16x16 MFMA, q=lane>>4, ln=lane&15):
//   A-frag: A[ln][4q+j];  B-frag: B[4q+j][ln];  C/D: C[4q+r][ln] (== B-frag).
// Identity-transpose: (M@I) relays A-frag of M into C/D positions.

struct Ck2 {
  half4 xbA[4], xsA[4];   // xb + second tensor (V for wave0, Q for wave1)
  float co4[4], co15;
};

__device__ __forceinline__ void load_ck2(
    Ck2& c, const _Float16* Kp, const _Float16* S, const float* co,
    size_t rowbase, int hoff, size_t cobase, int n, int q, int ln)
{
#pragma unroll
  for (int kt = 0; kt < 4; ++kt) {
    size_t idx = (rowbase + ln) * C_ + hoff + 16*kt + 4*q;
    c.xbA[kt] = *(const half4*)(Kp + idx);
    c.xsA[kt] = *(const half4*)(S  + idx);
  }
#pragma unroll
  for (int r = 0; r < 4; ++r) c.co4[r] = co[cobase + (size_t)n*K_ + 4*q + r];
  c.co15 = co[cobase + (size_t)n*K_ + 15];
}

__global__ __launch_bounds__(128, 1) void scan_kernel(
    const _Float16* __restrict__ Q, const _Float16* __restrict__ Kp,
    const _Float16* __restrict__ V,
    const float* __restrict__ coeff, const float* __restrict__ W1g, const float* __restrict__ b1g,
    const float* __restrict__ ln_w, const float* __restrict__ ln_b,
    _Float16* __restrict__ OF)
{
  const int bh = blockIdx.x;
  const int b = bh >> 5, h = bh & 31;
  const int tid = threadIdx.x;
  const int lane = tid & 63;
  const bool isP = tid < 64;                 // producer wave
  const int q = lane >> 4, ln = lane & 15;
  const int hoff = h * F_;
  const size_t cobase = (size_t)bh * L_;
  const size_t brow = (size_t)b * L_;

  __shared__ half4 gzs[4][4][64];            // [slot][t][lane], 8 KB

  // ---- replica state (both waves): single f16 W1, updated in place ----
  half4 W1f[4][4];
#pragma unroll
  for (int kt = 0; kt < 4; ++kt)
#pragma unroll
    for (int t = 0; t < 4; ++t) {
      half4 hv;
#pragma unroll
      for (int j = 0; j < 4; ++j)
        hv[j] = (_Float16)W1g[(size_t)h*F_*F_ + (size_t)(16*kt + 4*q + j)*F_ + 16*t + ln];
      W1f[kt][t] = hv;
    }
  float b1r[4], gamt[4], bett[4];
#pragma unroll
  for (int t = 0; t < 4; ++t) {
    b1r[t]  = b1g[hoff + 16*t + ln];
    gamt[t] = ln_w[hoff + 16*t + ln];
    bett[t] = ln_b[hoff + 16*t + ln];
  }
  half4 maskA, maskI;
#pragma unroll
  for (int j = 0; j < 4; ++j) {
    maskA[j] = (_Float16)((4*q + j <= ln) ? 1.f : 0.f);
    maskI[j] = (_Float16)((4*q + j == ln) ? 1.f : 0.f);
  }
  const f32x4 zf4 = (f32x4){0.f, 0.f, 0.f, 0.f};

  const _Float16* S = isP ? V : Q;

  // one pipeline iteration: producer handles chunk i (cur), prefetches i+1
  // into nxt; consumer prefetches chunk i into nxt, consumes chunk i-1 (cur).
  auto iter = [&](int i, Ck2& cur, Ck2& nxt) {
    half4 gzf[4];     // producer keeps own gZ across the barrier
    half4 xbTp[4];    // producer's xb^T A-frags
    float co15p = 0.f;

    if (isP) {
      if (i < NC_) {
        co15p = cur.co15;
        if (i + 1 < NC_)
          load_ck2(nxt, Kp, S, coeff, brow + (size_t)(i+1)*K_, hoff, cobase, i+1, q, ln);
        // transposes: tg = (xa - xb) into C/D; xb^T A-frag
        f32x4 tgD[4];
#pragma unroll
        for (int t = 0; t < 4; ++t) {
          half4 dd = cur.xsA[t] - cur.xbA[t];
          tgD[t] = __builtin_amdgcn_mfma_f32_16x16x16f16(dd, maskI, zf4, 0, 0, 0);
          f32x4 x = __builtin_amdgcn_mfma_f32_16x16x16f16(cur.xbA[t], maskI, zf4, 0, 0, 0);
          half4 v;
#pragma unroll
          for (int r = 0; r < 4; ++r) v[r] = (_Float16)x[r];
          xbTp[t] = v;
        }
        // za = xb@W1 + b1 (single f16 chain)
        f32x4 za[4];
#pragma unroll
        for (int t = 0; t < 4; ++t) {
          f32x4 zh = (f32x4){b1r[t], b1r[t], b1r[t], b1r[t]};
#pragma unroll
          for (int kt = 0; kt < 4; ++kt)
            zh = __builtin_amdgcn_mfma_f32_16x16x16f16(cur.xbA[kt], W1f[kt][t], zh, 0, 0, 0);
          za[t] = zh;
        }
        // LN-L2 backward -> gZ
#pragma unroll
        for (int r = 0; r < 4; ++r) {
          float zr[4], s1 = 0.f, s2 = 0.f;
#pragma unroll
          for (int t = 0; t < 4; ++t) { zr[t] = za[t][r]; s1 += zr[t]; s2 += zr[t]*zr[t]; }
          s1 = red16(s1); s2 = red16(s2);
          float mu = s1 * (1.f/F_);
          float istd = rsqrtf(s2 * (1.f/F_) - mu*mu + EPS_);
          float xh[4], gy[4], sg = 0.f, sx = 0.f;
#pragma unroll
          for (int t = 0; t < 4; ++t) {
            xh[t] = (zr[t] - mu) * istd;
            gy[t] = (gamt[t]*xh[t] + bett[t] - tgD[t][r]) * gamt[t];
            sg += gy[t]; sx += gy[t]*xh[t];
          }
          sg = red16(sg); sx = red16(sx);
          const float sc = istd * (1.f/F_);
#pragma unroll
          for (int t = 0; t < 4; ++t)
            gzf[t][r] = (_Float16)((F_*gy[t] - sg - xh[t]*sx) * sc);
        }
        // publish gZ
#pragma unroll
        for (int t = 0; t < 4; ++t) gzs[i & 3][t][lane] = gzf[t];
      }
    } else {
      if (i < NC_)
        load_ck2(nxt, Kp, S, coeff, brow + (size_t)i*K_, hoff, cobase, i, q, ln);
    }

    __syncthreads();

    if (isP) {
      if (i < NC_) {
        // cum for b1 update; delta; replica update
        f32x4 cum3[4];
#pragma unroll
        for (int t = 0; t < 4; ++t)
          cum3[t] = __builtin_amdgcn_mfma_f32_16x16x16f16(maskA, gzf[t], zf4, 0, 0, 0);
#pragma unroll
        for (int t = 0; t < 4; ++t) {
          float tmp = b1r[t] - co15p * cum3[t][3];
          b1r[t] = __shfl(tmp, 48 + ln, 64);
        }
#pragma unroll
        for (int mt = 0; mt < 4; ++mt)
#pragma unroll
          for (int t = 0; t < 4; ++t) {
            f32x4 d = __builtin_amdgcn_mfma_f32_16x16x16f16(xbTp[mt], gzf[t], zf4, 0, 0, 0);
            half4 dt;
#pragma unroll
            for (int r = 0; r < 4; ++r) dt[r] = (_Float16)(co15p * d[r]);
            W1f[mt][t] = W1f[mt][t] - dt;
          }
      }
    } else {
      if (i > 0) {
        const int jc = i - 1;
        const size_t rowbase = brow + (size_t)jc * K_;
        // receive gZ
        half4 gz[4];
#pragma unroll
        for (int t = 0; t < 4; ++t) gz[t] = gzs[jc & 3][t][lane];
        // transposes: xc into C/D (for output), xb^T A-frag (for delta)
        f32x4 xcsD[4]; half4 xbT[4];
#pragma unroll
        for (int t = 0; t < 4; ++t) {
          xcsD[t] = __builtin_amdgcn_mfma_f32_16x16x16f16(cur.xsA[t], maskI, zf4, 0, 0, 0);
          f32x4 x = __builtin_amdgcn_mfma_f32_16x16x16f16(cur.xbA[t], maskI, zf4, 0, 0, 0);
          half4 v;
#pragma unroll
          for (int r = 0; r < 4; ++r) v[r] = (_Float16)x[r];
          xbT[t] = v;
        }
        // attnT = xb@xc^T, masked -> A-frag of attn
        f32x4 at0 = zf4, at1 = zf4;
        at0 = __builtin_amdgcn_mfma_f32_16x16x16f16(cur.xbA[0], cur.xsA[0], at0, 0, 0, 0);
        at0 = __builtin_amdgcn_mfma_f32_16x16x16f16(cur.xbA[1], cur.xsA[1], at0, 0, 0, 0);
        at1 = __builtin_amdgcn_mfma_f32_16x16x16f16(cur.xbA[2], cur.xsA[2], at1, 0, 0, 0);
        at1 = __builtin_amdgcn_mfma_f32_16x16x16f16(cur.xbA[3], cur.xsA[3], at1, 0, 0, 0);
        f32x4 at = at0 + at1;
        half4 atf;
#pragma unroll
        for (int r = 0; r < 4; ++r) atf[r] = (_Float16)((4*q + r <= ln) ? at[r] : 0.f);
        // cum / ag
        f32x4 cum[4], ag[4];
#pragma unroll
        for (int t = 0; t < 4; ++t) {
          cum[t] = __builtin_amdgcn_mfma_f32_16x16x16f16(maskA, gz[t], zf4, 0, 0, 0);
          ag[t]  = __builtin_amdgcn_mfma_f32_16x16x16f16(atf,   gz[t], zf4, 0, 0, 0);
        }
        // zb = xc@W1 + b1 - co*(ag+cum)
        float zbf[4][4];
#pragma unroll
        for (int t = 0; t < 4; ++t) {
          f32x4 zh = zf4;
#pragma unroll
          for (int kt = 0; kt < 4; ++kt)
            zh = __builtin_amdgcn_mfma_f32_16x16x16f16(cur.xsA[kt], W1f[kt][t], zh, 0, 0, 0);
#pragma unroll
          for (int r = 0; r < 4; ++r)
            zbf[t][r] = zh[r] + b1r[t] - cur.co4[r]*(ag[t][r] + cum[t][r]);
        }
        // out = xc + LN(zb)
#pragma unroll
        for (int r = 0; r < 4; ++r) {
          float zr[4], s1 = 0.f, s2 = 0.f;
#pragma unroll
          for (int t = 0; t < 4; ++t) { zr[t] = zbf[t][r]; s1 += zr[t]; s2 += zr[t]*zr[t]; }
          s1 = red16(s1); s2 = red16(s2);
          float mu = s1 * (1.f/F_);
          float istd = rsqrtf(s2 * (1.f/F_) - mu*mu + EPS_);
#pragma unroll
          for (int t = 0; t < 4; ++t) {
            float ov = xcsD[t][r] + gamt[t]*((zr[t] - mu)*istd) + bett[t];
            OF[(rowbase + 4*q + r) * C_ + hoff + 16*t + ln] = (_Float16)ov;
          }
        }
        // replica updates (b1, W1) for chunk jc
#pragma unroll
        for (int t = 0; t < 4; ++t) {
          float tmp = b1r[t] - cur.co15 * cum[t][3];
          b1r[t] = __shfl(tmp, 48 + ln, 64);
        }
#pragma unroll
        for (int mt = 0; mt < 4; ++mt)
#pragma unroll
          for (int t = 0; t < 4; ++t) {
            f32x4 d = __builtin_amdgcn_mfma_f32_16x16x16f16(xbT[mt], gz[t], zf4, 0, 0, 0);
            half4 dt;
#pragma unroll
            for (int r = 0; r < 4; ++r) dt[r] = (_Float16)(cur.co15 * d[r]);
            W1f[mt][t] = W1f[mt][t] - dt;
          }
      }
    }
  };

  Ck2 cka, ckb;
  // producer preloads chunk 0 into cka; consumer's chunk 0 lands in ckb at iter 0
  if (isP) load_ck2(cka, Kp, S, coeff, brow, hoff, cobase, 0, q, ln);

  for (int i = 0; i < NC_; i += 2) {
    iter(i,     cka, ckb);
    iter(i + 1, ckb, cka);
  }
  iter(NC_, cka, ckb);   // final: consumer handles chunk NC_-1 (in cka)
}

extern "C" void kernel_launch(void* const* d_in, const int* in_sizes, int n_in,
                              void* d_out, int out_size, void* d_ws, size_t ws_size,
                              hipStream_t stream)
{
  const float* hid   = (const float*)d_in[0];
  const float* q_w   = (const float*)d_in[1];
  const float* k_w   = (const float*)d_in[2];
  const float* v_w   = (const float*)d_in[3];
  const float* o_w   = (const float*)d_in[4];
  const float* lin_w = (const float*)d_in[5];
  const float* lin_b = (const float*)d_in[6];
  const float* ln_w  = (const float*)d_in[7];
  const float* ln_b  = (const float*)d_in[8];
  const float* W1    = (const float*)d_in[9];
  const float* b1    = (const float*)d_in[10];
  float* out = (float*)d_out;

  const size_t BLC = (size_t)B_ * L_ * C_;
  const size_t CC  = (size_t)C_ * C_;
  _Float16* HF = (_Float16*)d_ws;               // hid f16; later scan output
  _Float16* WF = HF + BLC;
  _Float16* KF = WF + CC;
  _Float16* VF = KF + BLC;
  float*    CO = (float*)(VF + BLC);
  _Float16* QF = (_Float16*)d_out;              // Q f16 in d_out (dead before final GEMM)

  const int M = B_ * L_, N = C_, Kd = C_;
  dim3 gg(N / TN, M / TM);
  const int n8h = (int)(BLC / 8);
  const int n8w = (int)(CC / 8);

  cast_f16<<<(n8h+255)/256, 256, 0, stream>>>(hid, HF, n8h);
  cast_f16<<<(n8w+255)/256, 256, 0, stream>>>(q_w, WF, n8w);
  gemm_f16<_Float16><<<gg, 256, 0, stream>>>(HF, WF, QF, M, N, Kd);
  cast_f16<<<(n8w+255)/256, 256, 0, stream>>>(k_w, WF, n8w);
  gemm_f16<_Float16><<<gg, 256, 0, stream>>>(HF, WF, KF, M, N, Kd);
  cast_f16<<<(n8w+255)/256, 256, 0, stream>>>(v_w, WF, n8w);
  gemm_f16<_Float16><<<gg, 256, 0, stream>>>(HF, WF, VF, M, N, Kd);
  ilr_kernel<<<M / 16, 256, 0, stream>>>(hid, lin_w, lin_b, CO);
  scan_kernel<<<B_ * NH_, 128, 0, stream>>>(QF, KF, VF, CO, W1, b1, ln_w, ln_b, HF);
  cast_f16<<<(n8w+255)/256, 256, 0, stream>>>(o_w, WF, n8w);
  gemm_f16<float><<<gg, 256, 0, stream>>>(HF, WF, out, M, N, Kd);
}

// Round 14
// 1378.596 us; speedup vs baseline: 1.7923x; 1.0255x over previous
//
#include <hip/hip_runtime.h>
#include <hip/hip_bf16.h>

#define B_ 4
#define L_ 4096
#define C_ 2048
#define NH_ 32
#define K_ 16
#define F_ 64
#define NC_ 256
#define EPS_ 1e-6f

typedef _Float16 half8 __attribute__((ext_vector_type(8)));
typedef _Float16 half4 __attribute__((ext_vector_type(4)));
typedef float f32x4 __attribute__((ext_vector_type(4)));

// sum over 16-lane group via DPP (VALU pipe, no LDS): xor1, xor2, ror4, ror8
__device__ __forceinline__ float red16(float v) {
  int x;
  x = __builtin_amdgcn_update_dpp(0, __builtin_bit_cast(int, v), 0xB1, 0xF, 0xF, true);
  v += __builtin_bit_cast(float, x);
  x = __builtin_amdgcn_update_dpp(0, __builtin_bit_cast(int, v), 0x4E, 0xF, 0xF, true);
  v += __builtin_bit_cast(float, x);
  x = __builtin_amdgcn_update_dpp(0, __builtin_bit_cast(int, v), 0x124, 0xF, 0xF, true);
  v += __builtin_bit_cast(float, x);
  x = __builtin_amdgcn_update_dpp(0, __builtin_bit_cast(int, v), 0x128, 0xF, 0xF, true);
  v += __builtin_bit_cast(float, x);
  return v;
}

__device__ __forceinline__ void gl_lds16(const _Float16* g, _Float16* l) {
  __builtin_amdgcn_global_load_lds(
      (const __attribute__((address_space(1))) void*)g,
      (__attribute__((address_space(3))) void*)l, 16, 0, 0);
}

// ---------------- cast fp32 -> f16, 8 elems/thread ----------------
__global__ __launch_bounds__(256) void cast_f16(const float* __restrict__ in,
                                                _Float16* __restrict__ out, int n8) {
  int i = blockIdx.x * 256 + threadIdx.x;
  if (i >= n8) return;
  const float4* ip = (const float4*)in;
  float4 a = ip[2*i], b = ip[2*i+1];
  half8 o;
  o[0]=(_Float16)a.x; o[1]=(_Float16)a.y; o[2]=(_Float16)a.z; o[3]=(_Float16)a.w;
  o[4]=(_Float16)b.x; o[5]=(_Float16)b.y; o[6]=(_Float16)b.z; o[7]=(_Float16)b.w;
  ((half8*)out)[i] = o;
}

// ---------------- f16 MFMA GEMM v2: 256^2 tile, 8 waves, triple-buffer,
// counted vmcnt (never 0 in steady state), 1 barrier per K-tile ----------
#define GBM2 256
#define GBN2 256
#define GBK2 32

template<typename OT>
__global__ __launch_bounds__(512) void gemm_f16_v2(
    const _Float16* __restrict__ A, const _Float16* __restrict__ Bm,
    OT* __restrict__ C, int M, int N, int Kd)
{
  __shared__ __align__(16) _Float16 As[3][GBM2*GBK2];   // 3 x 16 KB
  __shared__ __align__(16) _Float16 Bs[3][GBM2*GBK2];   // 3 x 16 KB
  const int t = threadIdx.x;
  const int lane = t & 63;
  const int w = t >> 6;                 // 0..7
  const int bn = blockIdx.x, bm = blockIdx.y;
  const int wm = (w >> 2) * 128;        // 2 M-wave rows
  const int wn = (w & 3) * 64;          // 4 N-wave cols
  const int ln = lane & 15, q = lane >> 4;

  // staging: LDS slot s (16B) = row s>>2, chunk s&3 of a [256][32] f16 tile.
  // load0: s=t ; load1: s=t+512. Global source matches that mapping.
  const _Float16* gA0 = A  + ((long)(bm*GBM2 +        (t>>2)))*Kd + (t&3)*8;
  const _Float16* gA1 = A  + ((long)(bm*GBM2 + 128 +  (t>>2)))*Kd + (t&3)*8;
  const _Float16* gB0 = Bm + ((long)(bn*GBN2 +        (t>>2)))*Kd + (t&3)*8;
  const _Float16* gB1 = Bm + ((long)(bn*GBN2 + 128 +  (t>>2)))*Kd + (t&3)*8;

  auto stage = [&](int tile, int bi) {
    const long off = (long)tile * GBK2;
    gl_lds16(gA0 + off, &As[bi][(size_t)t*8]);
    gl_lds16(gA1 + off, &As[bi][(size_t)(t+512)*8]);
    gl_lds16(gB0 + off, &Bs[bi][(size_t)t*8]);
    gl_lds16(gB1 + off, &Bs[bi][(size_t)(t+512)*8]);
  };

  f32x4 acc[8][4];
#pragma unroll
  for (int i = 0; i < 8; ++i)
#pragma unroll
    for (int j = 0; j < 4; ++j) acc[i][j] = (f32x4){0.f,0.f,0.f,0.f};

  auto compute = [&](int kt) {
    const _Float16* as = As[kt % 3];
    const _Float16* bs = Bs[kt % 3];
    half8 bf[4];
#pragma unroll
    for (int ni = 0; ni < 4; ++ni)
      bf[ni] = *(const half8*)(bs + (size_t)(wn + ni*16 + ln)*GBK2 + q*8);
    __builtin_amdgcn_s_setprio(1);
#pragma unroll
    for (int mi = 0; mi < 8; ++mi) {
      half8 af = *(const half8*)(as + (size_t)(wm + mi*16 + ln)*GBK2 + q*8);
#pragma unroll
      for (int ni = 0; ni < 4; ++ni)
        acc[mi][ni] = __builtin_amdgcn_mfma_f32_16x16x32_f16(af, bf[ni], acc[mi][ni], 0, 0, 0);
    }
    __builtin_amdgcn_s_setprio(0);
  };

  const int NT = Kd / GBK2;             // 64
  // prologue: stage tiles 0,1 (8 loads in flight)
  stage(0, 0);
  stage(1, 1);

  for (int kt = 0; kt < NT - 2; ++kt) {
    __builtin_amdgcn_sched_barrier(0);
    __builtin_amdgcn_s_barrier();
    __builtin_amdgcn_sched_barrier(0);
    stage(kt + 2, (kt + 2) % 3);        // issue next-next tile; 12 in flight
    __builtin_amdgcn_sched_barrier(0);
    asm volatile("s_waitcnt vmcnt(8)" ::: "memory");  // tile kt landed
    __builtin_amdgcn_sched_barrier(0);
    compute(kt);
  }
  // tail: kt = NT-2 (no stage; tile NT-2 needs vmcnt(4))
  __builtin_amdgcn_sched_barrier(0);
  __builtin_amdgcn_s_barrier();
  __builtin_amdgcn_sched_barrier(0);
  asm volatile("s_waitcnt vmcnt(4)" ::: "memory");
  __builtin_amdgcn_sched_barrier(0);
  compute(NT - 2);
  // tail: kt = NT-1
  __builtin_amdgcn_sched_barrier(0);
  __builtin_amdgcn_s_barrier();
  __builtin_amdgcn_sched_barrier(0);
  asm volatile("s_waitcnt vmcnt(0)" ::: "memory");
  __builtin_amdgcn_sched_barrier(0);
  compute(NT - 1);

  // epilogue: C/D layout col=lane&15, row=(lane>>4)*4+reg
  const int cr = q * 4, cc = ln;
#pragma unroll
  for (int mi = 0; mi < 8; ++mi)
#pragma unroll
    for (int ni = 0; ni < 4; ++ni)
#pragma unroll
      for (int r = 0; r < 4; ++r) {
        long row = (long)bm*GBM2 + wm + mi*16 + cr + r;
        long col = (long)bn*GBN2 + wn + ni*16 + cc;
        C[row*(long)N + col] = (OT)acc[mi][ni][r];
      }
}

// ---------------- ilr / coeff (fp32) ----------------
__global__ __launch_bounds__(256) void ilr_kernel(
    const float* __restrict__ hid, const float* __restrict__ lin_w,
    const float* __restrict__ lin_b, float* __restrict__ coeff)
{
  const int t = threadIdx.x;
  const int lane = t & 63;
  const int w = t >> 6;
  const int row0 = blockIdx.x * 16 + w * 4;

  float4 hv[4][8];
#pragma unroll
  for (int r = 0; r < 4; ++r) {
    const float* hp = hid + (size_t)(row0 + r) * C_;
#pragma unroll
    for (int i = 0; i < 8; ++i) hv[r][i] = *(const float4*)(hp + i*256 + lane*4);
  }
  float res[4] = {0.f,0.f,0.f,0.f};
  for (int h = 0; h < NH_; ++h) {
    const float* wp = lin_w + (size_t)h * C_;
    float s[4] = {0.f,0.f,0.f,0.f};
#pragma unroll
    for (int i = 0; i < 8; ++i) {
      float4 wv = *(const float4*)(wp + i*256 + lane*4);
#pragma unroll
      for (int r = 0; r < 4; ++r)
        s[r] += hv[r][i].x*wv.x + hv[r][i].y*wv.y + hv[r][i].z*wv.z + hv[r][i].w*wv.w;
    }
#pragma unroll
    for (int o = 32; o > 0; o >>= 1)
#pragma unroll
      for (int r = 0; r < 4; ++r) s[r] += __shfl_xor(s[r], o, 64);
    if (lane == h) { res[0]=s[0]; res[1]=s[1]; res[2]=s[2]; res[3]=s[3]; }
  }
  if (lane < NH_) {
    float lb = lin_b[lane];
#pragma unroll
    for (int r = 0; r < 4; ++r) {
      int row = row0 + r;
      int b = row >> 12;
      int li = row & (L_ - 1);
      int k = li & (K_ - 1);
      float x = res[r] + lb;
      float sp = (x > 20.f) ? x : log1pf(expf(x));
      float v = (1.0f / (float)(k + 1)) * sp * (1.0f / (float)F_);
      coeff[((size_t)(b * NH_ + lane)) * L_ + li] = v;
    }
  }
}

// ---------------- TTT scan v8 (unchanged from R13) ----------
struct Ck2 {
  half4 xbA[4], xsA[4];   // xb + second tensor (V for wave0, Q for wave1)
  float co4[4], co15;
};

__device__ __forceinline__ void load_ck2(
    Ck2& c, const _Float16* Kp, const _Float16* S, const float* co,
    size_t rowbase, int hoff, size_t cobase, int n, int q, int ln)
{
#pragma unroll
  for (int kt = 0; kt < 4; ++kt) {
    size_t idx = (rowbase + ln) * C_ + hoff + 16*kt + 4*q;
    c.xbA[kt] = *(const half4*)(Kp + idx);
    c.xsA[kt] = *(const half4*)(S  + idx);
  }
#pragma unroll
  for (int r = 0; r < 4; ++r) c.co4[r] = co[cobase + (size_t)n*K_ + 4*q + r];
  c.co15 = co[cobase + (size_t)n*K_ + 15];
}

__global__ __launch_bounds__(128, 1) void scan_kernel(
    const _Float16* __restrict__ Q, const _Float16* __restrict__ Kp,
    const _Float16* __restrict__ V,
    const float* __restrict__ coeff, const float* __restrict__ W1g, const float* __restrict__ b1g,
    const float* __restrict__ ln_w, const float* __restrict__ ln_b,
    _Float16* __restrict__ OF)
{
  const int bh = blockIdx.x;
  const int b = bh >> 5, h = bh & 31;
  const int tid = threadIdx.x;
  const int lane = tid & 63;
  const bool isP = tid < 64;                 // producer wave
  const int q = lane >> 4, ln = lane & 15;
  const int hoff = h * F_;
  const size_t cobase = (size_t)bh * L_;
  const size_t brow = (size_t)b * L_;

  __shared__ half4 gzs[4][4][64];            // [slot][t][lane], 8 KB

  half4 W1f[4][4];
#pragma unroll
  for (int kt = 0; kt < 4; ++kt)
#pragma unroll
    for (int t = 0; t < 4; ++t) {
      half4 hv;
#pragma unroll
      for (int j = 0; j < 4; ++j)
        hv[j] = (_Float16)W1g[(size_t)h*F_*F_ + (size_t)(16*kt + 4*q + j)*F_ + 16*t + ln];
      W1f[kt][t] = hv;
    }
  float b1r[4], gamt[4], bett[4];
#pragma unroll
  for (int t = 0; t < 4; ++t) {
    b1r[t]  = b1g[hoff + 16*t + ln];
    gamt[t] = ln_w[hoff + 16*t + ln];
    bett[t] = ln_b[hoff + 16*t + ln];
  }
  half4 maskA, maskI;
#pragma unroll
  for (int j = 0; j < 4; ++j) {
    maskA[j] = (_Float16)((4*q + j <= ln) ? 1.f : 0.f);
    maskI[j] = (_Float16)((4*q + j == ln) ? 1.f : 0.f);
  }
  const f32x4 zf4 = (f32x4){0.f, 0.f, 0.f, 0.f};

  const _Float16* S = isP ? V : Q;

  auto iter = [&](int i, Ck2& cur, Ck2& nxt) {
    half4 gzf[4];
    half4 xbTp[4];
    float co15p = 0.f;

    if (isP) {
      if (i < NC_) {
        co15p = cur.co15;
        if (i + 1 < NC_)
          load_ck2(nxt, Kp, S, coeff, brow + (size_t)(i+1)*K_, hoff, cobase, i+1, q, ln);
        f32x4 tgD[4];
#pragma unroll
        for (int t = 0; t < 4; ++t) {
          half4 dd = cur.xsA[t] - cur.xbA[t];
          tgD[t] = __builtin_amdgcn_mfma_f32_16x16x16f16(dd, maskI, zf4, 0, 0, 0);
          f32x4 x = __builtin_amdgcn_mfma_f32_16x16x16f16(cur.xbA[t], maskI, zf4, 0, 0, 0);
          half4 v;
#pragma unroll
          for (int r = 0; r < 4; ++r) v[r] = (_Float16)x[r];
          xbTp[t] = v;
        }
        f32x4 za[4];
#pragma unroll
        for (int t = 0; t < 4; ++t) {
          f32x4 zh = (f32x4){b1r[t], b1r[t], b1r[t], b1r[t]};
#pragma unroll
          for (int kt = 0; kt < 4; ++kt)
            zh = __builtin_amdgcn_mfma_f32_16x16x16f16(cur.xbA[kt], W1f[kt][t], zh, 0, 0, 0);
          za[t] = zh;
        }
#pragma unroll
        for (int r = 0; r < 4; ++r) {
          float zr[4], s1 = 0.f, s2 = 0.f;
#pragma unroll
          for (int t = 0; t < 4; ++t) { zr[t] = za[t][r]; s1 += zr[t]; s2 += zr[t]*zr[t]; }
          s1 = red16(s1); s2 = red16(s2);
          float mu = s1 * (1.f/F_);
          float istd = rsqrtf(s2 * (1.f/F_) - mu*mu + EPS_);
          float xh[4], gy[4], sg = 0.f, sx = 0.f;
#pragma unroll
          for (int t = 0; t < 4; ++t) {
            xh[t] = (zr[t] - mu) * istd;
            gy[t] = (gamt[t]*xh[t] + bett[t] - tgD[t][r]) * gamt[t];
            sg += gy[t]; sx += gy[t]*xh[t];
          }
          sg = red16(sg); sx = red16(sx);
          const float sc = istd * (1.f/F_);
#pragma unroll
          for (int t = 0; t < 4; ++t)
            gzf[t][r] = (_Float16)((F_*gy[t] - sg - xh[t]*sx) * sc);
        }
#pragma unroll
        for (int t = 0; t < 4; ++t) gzs[i & 3][t][lane] = gzf[t];
      }
    } else {
      if (i < NC_)
        load_ck2(nxt, Kp, S, coeff, brow + (size_t)i*K_, hoff, cobase, i, q, ln);
    }

    __syncthreads();

    if (isP) {
      if (i < NC_) {
        f32x4 cum3[4];
#pragma unroll
        for (int t = 0; t < 4; ++t)
          cum3[t] = __builtin_amdgcn_mfma_f32_16x16x16f16(maskA, gzf[t], zf4, 0, 0, 0);
#pragma unroll
        for (int t = 0; t < 4; ++t) {
          float tmp = b1r[t] - co15p * cum3[t][3];
          b1r[t] = __shfl(tmp, 48 + ln, 64);
        }
#pragma unroll
        for (int mt = 0; mt < 4; ++mt)
#pragma unroll
          for (int t = 0; t < 4; ++t) {
            f32x4 d = __builtin_amdgcn_mfma_f32_16x16x16f16(xbTp[mt], gzf[t], zf4, 0, 0, 0);
            half4 dt;
#pragma unroll
            for (int r = 0; r < 4; ++r) dt[r] = (_Float16)(co15p * d[r]);
            W1f[mt][t] = W1f[mt][t] - dt;
          }
      }
    } else {
      if (i > 0) {
        const int jc = i - 1;
        const size_t rowbase = brow + (size_t)jc * K_;
        half4 gz[4];
#pragma unroll
        for (int t = 0; t < 4; ++t) gz[t] = gzs[jc & 3][t][lane];
        f32x4 xcsD[4]; half4 xbT[4];
#pragma unroll
        for (int t = 0; t < 4; ++t) {
          xcsD[t] = __builtin_amdgcn_mfma_f32_16x16x16f16(cur.xsA[t], maskI, zf4, 0, 0, 0);
          f32x4 x = __builtin_amdgcn_mfma_f32_16x16x16f16(cur.xbA[t], maskI, zf4, 0, 0, 0);
          half4 v;
#pragma unroll
          for (int r = 0; r < 4; ++r) v[r] = (_Float16)x[r];
          xbT[t] = v;
        }
        f32x4 at0 = zf4, at1 = zf4;
        at0 = __builtin_amdgcn_mfma_f32_16x16x16f16(cur.xbA[0], cur.xsA[0], at0, 0, 0, 0);
        at0 = __builtin_amdgcn_mfma_f32_16x16x16f16(cur.xbA[1], cur.xsA[1], at0, 0, 0, 0);
        at1 = __builtin_amdgcn_mfma_f32_16x16x16f16(cur.xbA[2], cur.xsA[2], at1, 0, 0, 0);
        at1 = __builtin_amdgcn_mfma_f32_16x16x16f16(cur.xbA[3], cur.xsA[3], at1, 0, 0, 0);
        f32x4 at = at0 + at1;
        half4 atf;
#pragma unroll
        for (int r = 0; r < 4; ++r) atf[r] = (_Float16)((4*q + r <= ln) ? at[r] : 0.f);
        f32x4 cum[4], ag[4];
#pragma unroll
        for (int t = 0; t < 4; ++t) {
          cum[t] = __builtin_amdgcn_mfma_f32_16x16x16f16(maskA, gz[t], zf4, 0, 0, 0);
          ag[t]  = __builtin_amdgcn_mfma_f32_16x16x16f16(atf,   gz[t], zf4, 0, 0, 0);
        }
        float zbf[4][4];
#pragma unroll
        for (int t = 0; t < 4; ++t) {
          f32x4 zh = zf4;
#pragma unroll
          for (int kt = 0; kt < 4; ++kt)
            zh = __builtin_amdgcn_mfma_f32_16x16x16f16(cur.xsA[kt], W1f[kt][t], zh, 0, 0, 0);
#pragma unroll
          for (int r = 0; r < 4; ++r)
            zbf[t][r] = zh[r] + b1r[t] - cur.co4[r]*(ag[t][r] + cum[t][r]);
        }
#pragma unroll
        for (int r = 0; r < 4; ++r) {
          float zr[4], s1 = 0.f, s2 = 0.f;
#pragma unroll
          for (int t = 0; t < 4; ++t) { zr[t] = zbf[t][r]; s1 += zr[t]; s2 += zr[t]*zr[t]; }
          s1 = red16(s1); s2 = red16(s2);
          float mu = s1 * (1.f/F_);
          float istd = rsqrtf(s2 * (1.f/F_) - mu*mu + EPS_);
#pragma unroll
          for (int t = 0; t < 4; ++t) {
            float ov = xcsD[t][r] + gamt[t]*((zr[t] - mu)*istd) + bett[t];
            OF[(rowbase + 4*q + r) * C_ + hoff + 16*t + ln] = (_Float16)ov;
          }
        }
#pragma unroll
        for (int t = 0; t < 4; ++t) {
          float tmp = b1r[t] - cur.co15 * cum[t][3];
          b1r[t] = __shfl(tmp, 48 + ln, 64);
        }
#pragma unroll
        for (int mt = 0; mt < 4; ++mt)
#pragma unroll
          for (int t = 0; t < 4; ++t) {
            f32x4 d = __builtin_amdgcn_mfma_f32_16x16x16f16(xbT[mt], gz[t], zf4, 0, 0, 0);
            half4 dt;
#pragma unroll
            for (int r = 0; r < 4; ++r) dt[r] = (_Float16)(cur.co15 * d[r]);
            W1f[mt][t] = W1f[mt][t] - dt;
          }
      }
    }
  };

  Ck2 cka, ckb;
  if (isP) load_ck2(cka, Kp, S, coeff, brow, hoff, cobase, 0, q, ln);

  for (int i = 0; i < NC_; i += 2) {
    iter(i,     cka, ckb);
    iter(i + 1, ckb, cka);
  }
  iter(NC_, cka, ckb);
}

extern "C" void kernel_launch(void* const* d_in, const int* in_sizes, int n_in,
                              void* d_out, int out_size, void* d_ws, size_t ws_size,
                              hipStream_t stream)
{
  const float* hid   = (const float*)d_in[0];
  const float* q_w   = (const float*)d_in[1];
  const float* k_w   = (const float*)d_in[2];
  const float* v_w   = (const float*)d_in[3];
  const float* o_w   = (const float*)d_in[4];
  const float* lin_w = (const float*)d_in[5];
  const float* lin_b = (const float*)d_in[6];
  const float* ln_w  = (const float*)d_in[7];
  const float* ln_b  = (const float*)d_in[8];
  const float* W1    = (const float*)d_in[9];
  const float* b1    = (const float*)d_in[10];
  float* out = (float*)d_out;

  const size_t BLC = (size_t)B_ * L_ * C_;
  const size_t CC  = (size_t)C_ * C_;
  _Float16* HF = (_Float16*)d_ws;               // hid f16; later scan output
  _Float16* WF = HF + BLC;
  _Float16* KF = WF + CC;
  _Float16* VF = KF + BLC;
  float*    CO = (float*)(VF + BLC);
  _Float16* QF = (_Float16*)d_out;              // Q f16 in d_out (dead before final GEMM)

  const int M = B_ * L_, N = C_, Kd = C_;
  dim3 gg2(N / GBN2, M / GBM2);                 // 8 x 64
  const int n8h = (int)(BLC / 8);
  const int n8w = (int)(CC / 8);

  cast_f16<<<(n8h+255)/256, 256, 0, stream>>>(hid, HF, n8h);
  cast_f16<<<(n8w+255)/256, 256, 0, stream>>>(q_w, WF, n8w);
  gemm_f16_v2<_Float16><<<gg2, 512, 0, stream>>>(HF, WF, QF, M, N, Kd);
  cast_f16<<<(n8w+255)/256, 256, 0, stream>>>(k_w, WF, n8w);
  gemm_f16_v2<_Float16><<<gg2, 512, 0, stream>>>(HF, WF, KF, M, N, Kd);
  cast_f16<<<(n8w+255)/256, 256, 0, stream>>>(v_w, WF, n8w);
  gemm_f16_v2<_Float16><<<gg2, 512, 0, stream>>>(HF, WF, VF, M, N, Kd);
  ilr_kernel<<<M / 16, 256, 0, stream>>>(hid, lin_w, lin_b, CO);
  scan_kernel<<<B_ * NH_, 128, 0, stream>>>(QF, KF, VF, CO, W1, b1, ln_w, ln_b, HF);
  cast_f16<<<(n8w+255)/256, 256, 0, stream>>>(o_w, WF, n8w);
  gemm_f16_v2<float><<<gg2, 512, 0, stream>>>(HF, WF, out, M, N, Kd);
}

// Round 15
// 1373.336 us; speedup vs baseline: 1.7991x; 1.0038x over previous
//
#include <hip/hip_runtime.h>
#include <hip/hip_bf16.h>

#define B_ 4
#define L_ 4096
#define C_ 2048
#define NH_ 32
#define K_ 16
#define F_ 64
#define NC_ 256
#define EPS_ 1e-6f

typedef _Float16 half8 __attribute__((ext_vector_type(8)));
typedef _Float16 half4 __attribute__((ext_vector_type(4)));
typedef float f32x4 __attribute__((ext_vector_type(4)));

// sum over 16-lane group via DPP (VALU pipe, no LDS): xor1, xor2, ror4, ror8
__device__ __forceinline__ float red16(float v) {
  int x;
  x = __builtin_amdgcn_update_dpp(0, __builtin_bit_cast(int, v), 0xB1, 0xF, 0xF, true);
  v += __builtin_bit_cast(float, x);
  x = __builtin_amdgcn_update_dpp(0, __builtin_bit_cast(int, v), 0x4E, 0xF, 0xF, true);
  v += __builtin_bit_cast(float, x);
  x = __builtin_amdgcn_update_dpp(0, __builtin_bit_cast(int, v), 0x124, 0xF, 0xF, true);
  v += __builtin_bit_cast(float, x);
  x = __builtin_amdgcn_update_dpp(0, __builtin_bit_cast(int, v), 0x128, 0xF, 0xF, true);
  v += __builtin_bit_cast(float, x);
  return v;
}

__device__ __forceinline__ void gl_lds16(const _Float16* g, _Float16* l) {
  __builtin_amdgcn_global_load_lds(
      (const __attribute__((address_space(1))) void*)g,
      (__attribute__((address_space(3))) void*)l, 16, 0, 0);
}

// ---------------- cast fp32 -> f16, 8 elems/thread ----------------
__global__ __launch_bounds__(256) void cast_f16(const float* __restrict__ in,
                                                _Float16* __restrict__ out, int n8) {
  int i = blockIdx.x * 256 + threadIdx.x;
  if (i >= n8) return;
  const float4* ip = (const float4*)in;
  float4 a = ip[2*i], b = ip[2*i+1];
  half8 o;
  o[0]=(_Float16)a.x; o[1]=(_Float16)a.y; o[2]=(_Float16)a.z; o[3]=(_Float16)a.w;
  o[4]=(_Float16)b.x; o[5]=(_Float16)b.y; o[6]=(_Float16)b.z; o[7]=(_Float16)b.w;
  ((half8*)out)[i] = o;
}

// ---------------- f16 MFMA GEMM v2 + LDS XOR swizzle ----------
// Tile [256][32] f16, 64B rows. Physical LDS 16B-chunk slot (row, cpos) holds
// logical k-chunk c = cpos ^ ((row>>1)&3)  (XOR involution; rule #21:
// linear global_load_lds dest + inverse-swizzled SOURCE + swizzled READ).
// Read of row=..+ln, chunk q hits all 32 banks balanced (was 8 banks, 4x).
#define GBM2 256
#define GBN2 256
#define GBK2 32

template<typename OT>
__global__ __launch_bounds__(512) void gemm_f16_v2(
    const _Float16* __restrict__ A, const _Float16* __restrict__ Bm,
    OT* __restrict__ C, int M, int N, int Kd)
{
  __shared__ __align__(16) _Float16 As[3][GBM2*GBK2];   // 3 x 16 KB
  __shared__ __align__(16) _Float16 Bs[3][GBM2*GBK2];   // 3 x 16 KB
  const int t = threadIdx.x;
  const int lane = t & 63;
  const int w = t >> 6;                 // 0..7
  const int bn = blockIdx.x, bm = blockIdx.y;
  const int wm = (w >> 2) * 128;        // 2 M-wave rows
  const int wn = (w & 3) * 64;          // 4 N-wave cols
  const int ln = lane & 15, q = lane >> 4;

  // source chunk for thread t's linear LDS slot (row=t>>2, cpos=t&3):
  const int schunk = (t & 3) ^ ((t >> 3) & 3);
  const _Float16* gA0 = A  + ((long)(bm*GBM2 +        (t>>2)))*Kd + schunk*8;
  const _Float16* gA1 = A  + ((long)(bm*GBM2 + 128 +  (t>>2)))*Kd + schunk*8;
  const _Float16* gB0 = Bm + ((long)(bn*GBN2 +        (t>>2)))*Kd + schunk*8;
  const _Float16* gB1 = Bm + ((long)(bn*GBN2 + 128 +  (t>>2)))*Kd + schunk*8;

  auto stage = [&](int tile, int bi) {
    const long off = (long)tile * GBK2;
    gl_lds16(gA0 + off, &As[bi][(size_t)t*8]);
    gl_lds16(gA1 + off, &As[bi][(size_t)(t+512)*8]);
    gl_lds16(gB0 + off, &Bs[bi][(size_t)t*8]);
    gl_lds16(gB1 + off, &Bs[bi][(size_t)(t+512)*8]);
  };

  f32x4 acc[8][4];
#pragma unroll
  for (int i = 0; i < 8; ++i)
#pragma unroll
    for (int j = 0; j < 4; ++j) acc[i][j] = (f32x4){0.f,0.f,0.f,0.f};

  const int sx = (ln >> 1) & 3;         // read-side swizzle selector
  const int qs = (q ^ sx) * 8;          // swizzled chunk offset (elems)

  auto compute = [&](int kt) {
    const _Float16* as = As[kt % 3];
    const _Float16* bs = Bs[kt % 3];
    half8 bf[4];
#pragma unroll
    for (int ni = 0; ni < 4; ++ni)
      bf[ni] = *(const half8*)(bs + (size_t)(wn + ni*16 + ln)*GBK2 + qs);
    __builtin_amdgcn_s_setprio(1);
#pragma unroll
    for (int mi = 0; mi < 8; ++mi) {
      half8 af = *(const half8*)(as + (size_t)(wm + mi*16 + ln)*GBK2 + qs);
#pragma unroll
      for (int ni = 0; ni < 4; ++ni)
        acc[mi][ni] = __builtin_amdgcn_mfma_f32_16x16x32_f16(af, bf[ni], acc[mi][ni], 0, 0, 0);
    }
    __builtin_amdgcn_s_setprio(0);
  };

  const int NT = Kd / GBK2;             // 64
  stage(0, 0);
  stage(1, 1);

  for (int kt = 0; kt < NT - 2; ++kt) {
    __builtin_amdgcn_sched_barrier(0);
    __builtin_amdgcn_s_barrier();
    __builtin_amdgcn_sched_barrier(0);
    stage(kt + 2, (kt + 2) % 3);        // issue next-next tile; 12 in flight
    __builtin_amdgcn_sched_barrier(0);
    asm volatile("s_waitcnt vmcnt(8)" ::: "memory");  // tile kt landed
    __builtin_amdgcn_sched_barrier(0);
    compute(kt);
  }
  __builtin_amdgcn_sched_barrier(0);
  __builtin_amdgcn_s_barrier();
  __builtin_amdgcn_sched_barrier(0);
  asm volatile("s_waitcnt vmcnt(4)" ::: "memory");
  __builtin_amdgcn_sched_barrier(0);
  compute(NT - 2);
  __builtin_amdgcn_sched_barrier(0);
  __builtin_amdgcn_s_barrier();
  __builtin_amdgcn_sched_barrier(0);
  asm volatile("s_waitcnt vmcnt(0)" ::: "memory");
  __builtin_amdgcn_sched_barrier(0);
  compute(NT - 1);

  const int cr = q * 4, cc = ln;
#pragma unroll
  for (int mi = 0; mi < 8; ++mi)
#pragma unroll
    for (int ni = 0; ni < 4; ++ni)
#pragma unroll
      for (int r = 0; r < 4; ++r) {
        long row = (long)bm*GBM2 + wm + mi*16 + cr + r;
        long col = (long)bn*GBN2 + wn + ni*16 + cc;
        C[row*(long)N + col] = (OT)acc[mi][ni][r];
      }
}

// ---------------- ilr / coeff (fp32) ----------------
__global__ __launch_bounds__(256) void ilr_kernel(
    const float* __restrict__ hid, const float* __restrict__ lin_w,
    const float* __restrict__ lin_b, float* __restrict__ coeff)
{
  const int t = threadIdx.x;
  const int lane = t & 63;
  const int w = t >> 6;
  const int row0 = blockIdx.x * 16 + w * 4;

  float4 hv[4][8];
#pragma unroll
  for (int r = 0; r < 4; ++r) {
    const float* hp = hid + (size_t)(row0 + r) * C_;
#pragma unroll
    for (int i = 0; i < 8; ++i) hv[r][i] = *(const float4*)(hp + i*256 + lane*4);
  }
  float res[4] = {0.f,0.f,0.f,0.f};
  for (int h = 0; h < NH_; ++h) {
    const float* wp = lin_w + (size_t)h * C_;
    float s[4] = {0.f,0.f,0.f,0.f};
#pragma unroll
    for (int i = 0; i < 8; ++i) {
      float4 wv = *(const float4*)(wp + i*256 + lane*4);
#pragma unroll
      for (int r = 0; r < 4; ++r)
        s[r] += hv[r][i].x*wv.x + hv[r][i].y*wv.y + hv[r][i].z*wv.z + hv[r][i].w*wv.w;
    }
#pragma unroll
    for (int o = 32; o > 0; o >>= 1)
#pragma unroll
      for (int r = 0; r < 4; ++r) s[r] += __shfl_xor(s[r], o, 64);
    if (lane == h) { res[0]=s[0]; res[1]=s[1]; res[2]=s[2]; res[3]=s[3]; }
  }
  if (lane < NH_) {
    float lb = lin_b[lane];
#pragma unroll
    for (int r = 0; r < 4; ++r) {
      int row = row0 + r;
      int b = row >> 12;
      int li = row & (L_ - 1);
      int k = li & (K_ - 1);
      float x = res[r] + lb;
      float sp = (x > 20.f) ? x : log1pf(expf(x));
      float v = (1.0f / (float)(k + 1)) * sp * (1.0f / (float)F_);
      coeff[((size_t)(b * NH_ + lane)) * L_ + li] = v;
    }
  }
}

// ---------------- TTT scan v8 (unchanged from R13) ----------
struct Ck2 {
  half4 xbA[4], xsA[4];   // xb + second tensor (V for wave0, Q for wave1)
  float co4[4], co15;
};

__device__ __forceinline__ void load_ck2(
    Ck2& c, const _Float16* Kp, const _Float16* S, const float* co,
    size_t rowbase, int hoff, size_t cobase, int n, int q, int ln)
{
#pragma unroll
  for (int kt = 0; kt < 4; ++kt) {
    size_t idx = (rowbase + ln) * C_ + hoff + 16*kt + 4*q;
    c.xbA[kt] = *(const half4*)(Kp + idx);
    c.xsA[kt] = *(const half4*)(S  + idx);
  }
#pragma unroll
  for (int r = 0; r < 4; ++r) c.co4[r] = co[cobase + (size_t)n*K_ + 4*q + r];
  c.co15 = co[cobase + (size_t)n*K_ + 15];
}

__global__ __launch_bounds__(128, 1) void scan_kernel(
    const _Float16* __restrict__ Q, const _Float16* __restrict__ Kp,
    const _Float16* __restrict__ V,
    const float* __restrict__ coeff, const float* __restrict__ W1g, const float* __restrict__ b1g,
    const float* __restrict__ ln_w, const float* __restrict__ ln_b,
    _Float16* __restrict__ OF)
{
  const int bh = blockIdx.x;
  const int b = bh >> 5, h = bh & 31;
  const int tid = threadIdx.x;
  const int lane = tid & 63;
  const bool isP = tid < 64;                 // producer wave
  const int q = lane >> 4, ln = lane & 15;
  const int hoff = h * F_;
  const size_t cobase = (size_t)bh * L_;
  const size_t brow = (size_t)b * L_;

  __shared__ half4 gzs[4][4][64];            // [slot][t][lane], 8 KB

  half4 W1f[4][4];
#pragma unroll
  for (int kt = 0; kt < 4; ++kt)
#pragma unroll
    for (int t = 0; t < 4; ++t) {
      half4 hv;
#pragma unroll
      for (int j = 0; j < 4; ++j)
        hv[j] = (_Float16)W1g[(size_t)h*F_*F_ + (size_t)(16*kt + 4*q + j)*F_ + 16*t + ln];
      W1f[kt][t] = hv;
    }
  float b1r[4], gamt[4], bett[4];
#pragma unroll
  for (int t = 0; t < 4; ++t) {
    b1r[t]  = b1g[hoff + 16*t + ln];
    gamt[t] = ln_w[hoff + 16*t + ln];
    bett[t] = ln_b[hoff + 16*t + ln];
  }
  half4 maskA, maskI;
#pragma unroll
  for (int j = 0; j < 4; ++j) {
    maskA[j] = (_Float16)((4*q + j <= ln) ? 1.f : 0.f);
    maskI[j] = (_Float16)((4*q + j == ln) ? 1.f : 0.f);
  }
  const f32x4 zf4 = (f32x4){0.f, 0.f, 0.f, 0.f};

  const _Float16* S = isP ? V : Q;

  auto iter = [&](int i, Ck2& cur, Ck2& nxt) {
    half4 gzf[4];
    half4 xbTp[4];
    float co15p = 0.f;

    if (isP) {
      if (i < NC_) {
        co15p = cur.co15;
        if (i + 1 < NC_)
          load_ck2(nxt, Kp, S, coeff, brow + (size_t)(i+1)*K_, hoff, cobase, i+1, q, ln);
        f32x4 tgD[4];
#pragma unroll
        for (int t = 0; t < 4; ++t) {
          half4 dd = cur.xsA[t] - cur.xbA[t];
          tgD[t] = __builtin_amdgcn_mfma_f32_16x16x16f16(dd, maskI, zf4, 0, 0, 0);
          f32x4 x = __builtin_amdgcn_mfma_f32_16x16x16f16(cur.xbA[t], maskI, zf4, 0, 0, 0);
          half4 v;
#pragma unroll
          for (int r = 0; r < 4; ++r) v[r] = (_Float16)x[r];
          xbTp[t] = v;
        }
        f32x4 za[4];
#pragma unroll
        for (int t = 0; t < 4; ++t) {
          f32x4 zh = (f32x4){b1r[t], b1r[t], b1r[t], b1r[t]};
#pragma unroll
          for (int kt = 0; kt < 4; ++kt)
            zh = __builtin_amdgcn_mfma_f32_16x16x16f16(cur.xbA[kt], W1f[kt][t], zh, 0, 0, 0);
          za[t] = zh;
        }
#pragma unroll
        for (int r = 0; r < 4; ++r) {
          float zr[4], s1 = 0.f, s2 = 0.f;
#pragma unroll
          for (int t = 0; t < 4; ++t) { zr[t] = za[t][r]; s1 += zr[t]; s2 += zr[t]*zr[t]; }
          s1 = red16(s1); s2 = red16(s2);
          float mu = s1 * (1.f/F_);
          float istd = rsqrtf(s2 * (1.f/F_) - mu*mu + EPS_);
          float xh[4], gy[4], sg = 0.f, sx = 0.f;
#pragma unroll
          for (int t = 0; t < 4; ++t) {
            xh[t] = (zr[t] - mu) * istd;
            gy[t] = (gamt[t]*xh[t] + bett[t] - tgD[t][r]) * gamt[t];
            sg += gy[t]; sx += gy[t]*xh[t];
          }
          sg = red16(sg); sx = red16(sx);
          const float sc = istd * (1.f/F_);
#pragma unroll
          for (int t = 0; t < 4; ++t)
            gzf[t][r] = (_Float16)((F_*gy[t] - sg - xh[t]*sx) * sc);
        }
#pragma unroll
        for (int t = 0; t < 4; ++t) gzs[i & 3][t][lane] = gzf[t];
      }
    } else {
      if (i < NC_)
        load_ck2(nxt, Kp, S, coeff, brow + (size_t)i*K_, hoff, cobase, i, q, ln);
    }

    __syncthreads();

    if (isP) {
      if (i < NC_) {
        f32x4 cum3[4];
#pragma unroll
        for (int t = 0; t < 4; ++t)
          cum3[t] = __builtin_amdgcn_mfma_f32_16x16x16f16(maskA, gzf[t], zf4, 0, 0, 0);
#pragma unroll
        for (int t = 0; t < 4; ++t) {
          float tmp = b1r[t] - co15p * cum3[t][3];
          b1r[t] = __shfl(tmp, 48 + ln, 64);
        }
#pragma unroll
        for (int mt = 0; mt < 4; ++mt)
#pragma unroll
          for (int t = 0; t < 4; ++t) {
            f32x4 d = __builtin_amdgcn_mfma_f32_16x16x16f16(xbTp[mt], gzf[t], zf4, 0, 0, 0);
            half4 dt;
#pragma unroll
            for (int r = 0; r < 4; ++r) dt[r] = (_Float16)(co15p * d[r]);
            W1f[mt][t] = W1f[mt][t] - dt;
          }
      }
    } else {
      if (i > 0) {
        const int jc = i - 1;
        const size_t rowbase = brow + (size_t)jc * K_;
        half4 gz[4];
#pragma unroll
        for (int t = 0; t < 4; ++t) gz[t] = gzs[jc & 3][t][lane];
        f32x4 xcsD[4]; half4 xbT[4];
#pragma unroll
        for (int t = 0; t < 4; ++t) {
          xcsD[t] = __builtin_amdgcn_mfma_f32_16x16x16f16(cur.xsA[t], maskI, zf4, 0, 0, 0);
          f32x4 x = __builtin_amdgcn_mfma_f32_16x16x16f16(cur.xbA[t], maskI, zf4, 0, 0, 0);
          half4 v;
#pragma unroll
          for (int r = 0; r < 4; ++r) v[r] = (_Float16)x[r];
          xbT[t] = v;
        }
        f32x4 at0 = zf4, at1 = zf4;
        at0 = __builtin_amdgcn_mfma_f32_16x16x16f16(cur.xbA[0], cur.xsA[0], at0, 0, 0, 0);
        at0 = __builtin_amdgcn_mfma_f32_16x16x16f16(cur.xbA[1], cur.xsA[1], at0, 0, 0, 0);
        at1 = __builtin_amdgcn_mfma_f32_16x16x16f16(cur.xbA[2], cur.xsA[2], at1, 0, 0, 0);
        at1 = __builtin_amdgcn_mfma_f32_16x16x16f16(cur.xbA[3], cur.xsA[3], at1, 0, 0, 0);
        f32x4 at = at0 + at1;
        half4 atf;
#pragma unroll
        for (int r = 0; r < 4; ++r) atf[r] = (_Float16)((4*q + r <= ln) ? at[r] : 0.f);
        f32x4 cum[4], ag[4];
#pragma unroll
        for (int t = 0; t < 4; ++t) {
          cum[t] = __builtin_amdgcn_mfma_f32_16x16x16f16(maskA, gz[t], zf4, 0, 0, 0);
          ag[t]  = __builtin_amdgcn_mfma_f32_16x16x16f16(atf,   gz[t], zf4, 0, 0, 0);
        }
        float zbf[4][4];
#pragma unroll
        for (int t = 0; t < 4; ++t) {
          f32x4 zh = zf4;
#pragma unroll
          for (int kt = 0; kt < 4; ++kt)
            zh = __builtin_amdgcn_mfma_f32_16x16x16f16(cur.xsA[kt], W1f[kt][t], zh, 0, 0, 0);
#pragma unroll
          for (int r = 0; r < 4; ++r)
            zbf[t][r] = zh[r] + b1r[t] - cur.co4[r]*(ag[t][r] + cum[t][r]);
        }
#pragma unroll
        for (int r = 0; r < 4; ++r) {
          float zr[4], s1 = 0.f, s2 = 0.f;
#pragma unroll
          for (int t = 0; t < 4; ++t) { zr[t] = zbf[t][r]; s1 += zr[t]; s2 += zr[t]*zr[t]; }
          s1 = red16(s1); s2 = red16(s2);
          float mu = s1 * (1.f/F_);
          float istd = rsqrtf(s2 * (1.f/F_) - mu*mu + EPS_);
#pragma unroll
          for (int t = 0; t < 4; ++t) {
            float ov = xcsD[t][r] + gamt[t]*((zr[t] - mu)*istd) + bett[t];
            OF[(rowbase + 4*q + r) * C_ + hoff + 16*t + ln] = (_Float16)ov;
          }
        }
#pragma unroll
        for (int t = 0; t < 4; ++t) {
          float tmp = b1r[t] - cur.co15 * cum[t][3];
          b1r[t] = __shfl(tmp, 48 + ln, 64);
        }
#pragma unroll
        for (int mt = 0; mt < 4; ++mt)
#pragma unroll
          for (int t = 0; t < 4; ++t) {
            f32x4 d = __builtin_amdgcn_mfma_f32_16x16x16f16(xbT[mt], gz[t], zf4, 0, 0, 0);
            half4 dt;
#pragma unroll
            for (int r = 0; r < 4; ++r) dt[r] = (_Float16)(cur.co15 * d[r]);
            W1f[mt][t] = W1f[mt][t] - dt;
          }
      }
    }
  };

  Ck2 cka, ckb;
  if (isP) load_ck2(cka, Kp, S, coeff, brow, hoff, cobase, 0, q, ln);

  for (int i = 0; i < NC_; i += 2) {
    iter(i,     cka, ckb);
    iter(i + 1, ckb, cka);
  }
  iter(NC_, cka, ckb);
}

extern "C" void kernel_launch(void* const* d_in, const int* in_sizes, int n_in,
                              void* d_out, int out_size, void* d_ws, size_t ws_size,
                              hipStream_t stream)
{
  const float* hid   = (const float*)d_in[0];
  const float* q_w   = (const float*)d_in[1];
  const float* k_w   = (const float*)d_in[2];
  const float* v_w   = (const float*)d_in[3];
  const float* o_w   = (const float*)d_in[4];
  const float* lin_w = (const float*)d_in[5];
  const float* lin_b = (const float*)d_in[6];
  const float* ln_w  = (const float*)d_in[7];
  const float* ln_b  = (const float*)d_in[8];
  const float* W1    = (const float*)d_in[9];
  const float* b1    = (const float*)d_in[10];
  float* out = (float*)d_out;

  const size_t BLC = (size_t)B_ * L_ * C_;
  const size_t CC  = (size_t)C_ * C_;
  _Float16* HF = (_Float16*)d_ws;               // hid f16; later scan output
  _Float16* WF = HF + BLC;
  _Float16* KF = WF + CC;
  _Float16* VF = KF + BLC;
  float*    CO = (float*)(VF + BLC);
  _Float16* QF = (_Float16*)d_out;              // Q f16 in d_out (dead before final GEMM)

  const int M = B_ * L_, N = C_, Kd = C_;
  dim3 gg2(N / GBN2, M / GBM2);                 // 8 x 64
  const int n8h = (int)(BLC / 8);
  const int n8w = (int)(CC / 8);

  cast_f16<<<(n8h+255)/256, 256, 0, stream>>>(hid, HF, n8h);
  cast_f16<<<(n8w+255)/256, 256, 0, stream>>>(q_w, WF, n8w);
  gemm_f16_v2<_Float16><<<gg2, 512, 0, stream>>>(HF, WF, QF, M, N, Kd);
  cast_f16<<<(n8w+255)/256, 256, 0, stream>>>(k_w, WF, n8w);
  gemm_f16_v2<_Float16><<<gg2, 512, 0, stream>>>(HF, WF, KF, M, N, Kd);
  cast_f16<<<(n8w+255)/256, 256, 0, stream>>>(v_w, WF, n8w);
  gemm_f16_v2<_Float16><<<gg2, 512, 0, stream>>>(HF, WF, VF, M, N, Kd);
  ilr_kernel<<<M / 16, 256, 0, stream>>>(hid, lin_w, lin_b, CO);
  scan_kernel<<<B_ * NH_, 128, 0, stream>>>(QF, KF, VF, CO, W1, b1, ln_w, ln_b, HF);
  cast_f16<<<(n8w+255)/256, 256, 0, stream>>>(o_w, WF, n8w);
  gemm_f16_v2<float><<<gg2, 512, 0, stream>>>(HF, WF, out, M, N, Kd);
}

// Round 16
// 1293.358 us; speedup vs baseline: 1.9104x; 1.0618x over previous
//
#include <hip/hip_runtime.h>
#include <hip/hip_bf16.h>

#define B_ 4
#define L_ 4096
#define C_ 2048
#define NH_ 32
#define K_ 16
#define F_ 64
#define NC_ 256
#define EPS_ 1e-6f

typedef _Float16 half8 __attribute__((ext_vector_type(8)));
typedef _Float16 half4 __attribute__((ext_vector_type(4)));
typedef float f32x4 __attribute__((ext_vector_type(4)));

__device__ __forceinline__ float red16(float v) {
  int x;
  x = __builtin_amdgcn_update_dpp(0, __builtin_bit_cast(int, v), 0xB1, 0xF, 0xF, true);
  v += __builtin_bit_cast(float, x);
  x = __builtin_amdgcn_update_dpp(0, __builtin_bit_cast(int, v), 0x4E, 0xF, 0xF, true);
  v += __builtin_bit_cast(float, x);
  x = __builtin_amdgcn_update_dpp(0, __builtin_bit_cast(int, v), 0x124, 0xF, 0xF, true);
  v += __builtin_bit_cast(float, x);
  x = __builtin_amdgcn_update_dpp(0, __builtin_bit_cast(int, v), 0x128, 0xF, 0xF, true);
  v += __builtin_bit_cast(float, x);
  return v;
}

__device__ __forceinline__ void gl_lds16(const _Float16* g, _Float16* l) {
  __builtin_amdgcn_global_load_lds(
      (const __attribute__((address_space(1))) void*)g,
      (__attribute__((address_space(3))) void*)l, 16, 0, 0);
}

// ---------------- cast fp32 -> f16, 8 elems/thread ----------------
__global__ __launch_bounds__(256) void cast_f16(const float* __restrict__ in,
                                                _Float16* __restrict__ out, int n8) {
  int i = blockIdx.x * 256 + threadIdx.x;
  if (i >= n8) return;
  const float4* ip = (const float4*)in;
  float4 a = ip[2*i], b = ip[2*i+1];
  half8 o;
  o[0]=(_Float16)a.x; o[1]=(_Float16)a.y; o[2]=(_Float16)a.z; o[3]=(_Float16)a.w;
  o[4]=(_Float16)b.x; o[5]=(_Float16)b.y; o[6]=(_Float16)b.z; o[7]=(_Float16)b.w;
  ((half8*)out)[i] = o;
}

// ---------------- f16 MFMA GEMM v3: 256x256, BK=64, 8 waves (2x4),
// 2-deep LDS double-buffer (128 KB), 4-phase quadrant schedule,
// counted vmcnt BEFORE barrier (cross-wave visibility), st_16x32 swizzle.
// Output split across up to 3 region pointers (each region N=2048). ----------
#define BM3 256
#define BN3 256
#define BK3 64

template<typename OT>
__global__ __launch_bounds__(512, 2) void gemm_f16_v3(
    const _Float16* __restrict__ A, const _Float16* __restrict__ Bm,
    OT* __restrict__ C0, OT* __restrict__ C1, OT* __restrict__ C2, int Kd)
{
  __shared__ __align__(16) _Float16 As[2][2][128*64];   // [dbuf][half] 16KB each
  __shared__ __align__(16) _Float16 Bs[2][2][128*64];
  const int t = threadIdx.x;
  const int lane = t & 63;
  const int w = t >> 6;
  const int wr = w >> 2, wc = w & 3;      // 2 x 4 waves; wave tile 128x64
  const int bn = blockIdx.x, bm = blockIdx.y;
  const int ln = lane & 15, q = lane >> 4;

  // staging: thread t -> rows (srow, 64+srow), phys chunk sc; logical chunk
  // clg = sc ^ 2*((row>>2)&1)  (same for both rows since 64 ≡ 0 mod 8 rows)
  const int srow = t >> 3, sc = t & 7;
  const int clg = sc ^ (2 * ((srow >> 2) & 1));

  auto stageA = [&](int kt, int h, int db) {
    const _Float16* g = A + ((long)(bm*BM3 + h*128 + srow))*Kd + (long)kt*BK3 + clg*8;
    gl_lds16(g,          &As[db][h][(size_t)srow*64 + sc*8]);
    gl_lds16(g + 64*Kd,  &As[db][h][(size_t)(64+srow)*64 + sc*8]);
  };
  auto stageB = [&](int kt, int h, int db) {
    const _Float16* g = Bm + ((long)(bn*BN3 + h*128 + srow))*Kd + (long)kt*BK3 + clg*8;
    gl_lds16(g,          &Bs[db][h][(size_t)srow*64 + sc*8]);
    gl_lds16(g + 64*Kd,  &Bs[db][h][(size_t)(64+srow)*64 + sc*8]);
  };

  f32x4 acc[8][4];
#pragma unroll
  for (int i = 0; i < 8; ++i)
#pragma unroll
    for (int j = 0; j < 4; ++j) acc[i][j] = (f32x4){0.f,0.f,0.f,0.f};

  half8 af[8][2], bf[4][2];

  // prologue: stage all 4 half-tiles of kt=0 into dbuf 0 (8 loads)
  stageA(0, 0, 0); stageA(0, 1, 0); stageB(0, 0, 0); stageB(0, 1, 0);

  const int NT = Kd / BK3;                // 32
  for (int kt = 0; kt < NT; ++kt) {
    const int db = kt & 1;
    const bool more = (kt + 1 < NT);
    if (more) { stageA(kt+1, 0, db^1); stageB(kt+1, 0, db^1); }   // +4 -> 12
    __builtin_amdgcn_sched_barrier(0);
    if (more) asm volatile("s_waitcnt vmcnt(4)" ::: "memory");    // kt's 8 landed
    else      asm volatile("s_waitcnt vmcnt(0)" ::: "memory");
    __builtin_amdgcn_sched_barrier(0);
    __builtin_amdgcn_s_barrier();        // all waves' kt loads globally visible
    __builtin_amdgcn_sched_barrier(0);

    const _Float16* ap = &As[db][wr][0];
    const _Float16* bp = &Bs[db][wc >> 1][0];
    const int lcb = (wc & 1) * 64;

    // ph0: A rows 0-63 (mi 0-3) + B cols 0-31 (ni 0-1); quadrant q0
#pragma unroll
    for (int mi = 0; mi < 4; ++mi)
#pragma unroll
      for (int ks = 0; ks < 2; ++ks) {
        int lr = mi*16 + ln;
        int cp = (ks*4 + q) ^ (2*((lr>>2)&1));
        af[mi][ks] = *(const half8*)(ap + (size_t)lr*64 + cp*8);
      }
#pragma unroll
    for (int ni = 0; ni < 2; ++ni)
#pragma unroll
      for (int ks = 0; ks < 2; ++ks) {
        int lc = lcb + ni*16 + ln;
        int cp = (ks*4 + q) ^ (2*((lc>>2)&1));
        bf[ni][ks] = *(const half8*)(bp + (size_t)lc*64 + cp*8);
      }
    __builtin_amdgcn_s_setprio(1);
#pragma unroll
    for (int mi = 0; mi < 4; ++mi)
#pragma unroll
      for (int ni = 0; ni < 2; ++ni)
#pragma unroll
        for (int ks = 0; ks < 2; ++ks)
          acc[mi][ni] = __builtin_amdgcn_mfma_f32_16x16x32_f16(af[mi][ks], bf[ni][ks], acc[mi][ni], 0, 0, 0);
    __builtin_amdgcn_s_setprio(0);
    if (more) stageA(kt+1, 1, db^1);     // +2

    // ph1: A rows 64-127 (mi 4-7); quadrant q1
#pragma unroll
    for (int mi = 4; mi < 8; ++mi)
#pragma unroll
      for (int ks = 0; ks < 2; ++ks) {
        int lr = mi*16 + ln;
        int cp = (ks*4 + q) ^ (2*((lr>>2)&1));
        af[mi][ks] = *(const half8*)(ap + (size_t)lr*64 + cp*8);
      }
    __builtin_amdgcn_s_setprio(1);
#pragma unroll
    for (int mi = 4; mi < 8; ++mi)
#pragma unroll
      for (int ni = 0; ni < 2; ++ni)
#pragma unroll
        for (int ks = 0; ks < 2; ++ks)
          acc[mi][ni] = __builtin_amdgcn_mfma_f32_16x16x32_f16(af[mi][ks], bf[ni][ks], acc[mi][ni], 0, 0, 0);
    __builtin_amdgcn_s_setprio(0);
    if (more) stageB(kt+1, 1, db^1);     // +2 -> 8 outstanding at iter end

    // ph2: B cols 32-63 (ni 2-3); quadrant q2 (mi 4-7)
#pragma unroll
    for (int ni = 2; ni < 4; ++ni)
#pragma unroll
      for (int ks = 0; ks < 2; ++ks) {
        int lc = lcb + ni*16 + ln;
        int cp = (ks*4 + q) ^ (2*((lc>>2)&1));
        bf[ni][ks] = *(const half8*)(bp + (size_t)lc*64 + cp*8);
      }
    __builtin_amdgcn_s_setprio(1);
#pragma unroll
    for (int mi = 4; mi < 8; ++mi)
#pragma unroll
      for (int ni = 2; ni < 4; ++ni)
#pragma unroll
        for (int ks = 0; ks < 2; ++ks)
          acc[mi][ni] = __builtin_amdgcn_mfma_f32_16x16x32_f16(af[mi][ks], bf[ni][ks], acc[mi][ni], 0, 0, 0);
    __builtin_amdgcn_s_setprio(0);

    // ph3: quadrant q3 (mi 0-3 x ni 2-3), all frags live
    __builtin_amdgcn_s_setprio(1);
#pragma unroll
    for (int mi = 0; mi < 4; ++mi)
#pragma unroll
      for (int ni = 2; ni < 4; ++ni)
#pragma unroll
        for (int ks = 0; ks < 2; ++ks)
          acc[mi][ni] = __builtin_amdgcn_mfma_f32_16x16x32_f16(af[mi][ks], bf[ni][ks], acc[mi][ni], 0, 0, 0);
    __builtin_amdgcn_s_setprio(0);

    __builtin_amdgcn_sched_barrier(0);
    __builtin_amdgcn_s_barrier();        // protects dbuf db^1... (next iter stages db)
    __builtin_amdgcn_sched_barrier(0);
  }

  // epilogue: region select (uniform per block), each region row-stride 2048
  const int reg = bn >> 3, bnl = bn & 7;
  OT* C = (reg == 0) ? C0 : ((reg == 1) ? C1 : C2);
  const int cr = q * 4;
#pragma unroll
  for (int mi = 0; mi < 8; ++mi)
#pragma unroll
    for (int ni = 0; ni < 4; ++ni)
#pragma unroll
      for (int r = 0; r < 4; ++r) {
        long row = (long)bm*BM3 + wr*128 + mi*16 + cr + r;
        long col = (long)bnl*256 + wc*64 + ni*16 + ln;
        C[row*2048L + col] = (OT)acc[mi][ni][r];
      }
}

// ---------------- ilr / coeff (fp32) ----------------
__global__ __launch_bounds__(256) void ilr_kernel(
    const float* __restrict__ hid, const float* __restrict__ lin_w,
    const float* __restrict__ lin_b, float* __restrict__ coeff)
{
  const int t = threadIdx.x;
  const int lane = t & 63;
  const int w = t >> 6;
  const int row0 = blockIdx.x * 16 + w * 4;

  float4 hv[4][8];
#pragma unroll
  for (int r = 0; r < 4; ++r) {
    const float* hp = hid + (size_t)(row0 + r) * C_;
#pragma unroll
    for (int i = 0; i < 8; ++i) hv[r][i] = *(const float4*)(hp + i*256 + lane*4);
  }
  float res[4] = {0.f,0.f,0.f,0.f};
  for (int h = 0; h < NH_; ++h) {
    const float* wp = lin_w + (size_t)h * C_;
    float s[4] = {0.f,0.f,0.f,0.f};
#pragma unroll
    for (int i = 0; i < 8; ++i) {
      float4 wv = *(const float4*)(wp + i*256 + lane*4);
#pragma unroll
      for (int r = 0; r < 4; ++r)
        s[r] += hv[r][i].x*wv.x + hv[r][i].y*wv.y + hv[r][i].z*wv.z + hv[r][i].w*wv.w;
    }
#pragma unroll
    for (int o = 32; o > 0; o >>= 1)
#pragma unroll
      for (int r = 0; r < 4; ++r) s[r] += __shfl_xor(s[r], o, 64);
    if (lane == h) { res[0]=s[0]; res[1]=s[1]; res[2]=s[2]; res[3]=s[3]; }
  }
  if (lane < NH_) {
    float lb = lin_b[lane];
#pragma unroll
    for (int r = 0; r < 4; ++r) {
      int row = row0 + r;
      int b = row >> 12;
      int li = row & (L_ - 1);
      int k = li & (K_ - 1);
      float x = res[r] + lb;
      float sp = (x > 20.f) ? x : log1pf(expf(x));
      float v = (1.0f / (float)(k + 1)) * sp * (1.0f / (float)F_);
      coeff[((size_t)(b * NH_ + lane)) * L_ + li] = v;
    }
  }
}

// ---------------- TTT scan v8 (unchanged from R13) ----------
struct Ck2 {
  half4 xbA[4], xsA[4];
  float co4[4], co15;
};

__device__ __forceinline__ void load_ck2(
    Ck2& c, const _Float16* Kp, const _Float16* S, const float* co,
    size_t rowbase, int hoff, size_t cobase, int n, int q, int ln)
{
#pragma unroll
  for (int kt = 0; kt < 4; ++kt) {
    size_t idx = (rowbase + ln) * C_ + hoff + 16*kt + 4*q;
    c.xbA[kt] = *(const half4*)(Kp + idx);
    c.xsA[kt] = *(const half4*)(S  + idx);
  }
#pragma unroll
  for (int r = 0; r < 4; ++r) c.co4[r] = co[cobase + (size_t)n*K_ + 4*q + r];
  c.co15 = co[cobase + (size_t)n*K_ + 15];
}

__global__ __launch_bounds__(128, 1) void scan_kernel(
    const _Float16* __restrict__ Q, const _Float16* __restrict__ Kp,
    const _Float16* __restrict__ V,
    const float* __restrict__ coeff, const float* __restrict__ W1g, const float* __restrict__ b1g,
    const float* __restrict__ ln_w, const float* __restrict__ ln_b,
    _Float16* __restrict__ OF)
{
  const int bh = blockIdx.x;
  const int b = bh >> 5, h = bh & 31;
  const int tid = threadIdx.x;
  const int lane = tid & 63;
  const bool isP = tid < 64;
  const int q = lane >> 4, ln = lane & 15;
  const int hoff = h * F_;
  const size_t cobase = (size_t)bh * L_;
  const size_t brow = (size_t)b * L_;

  __shared__ half4 gzs[4][4][64];

  half4 W1f[4][4];
#pragma unroll
  for (int kt = 0; kt < 4; ++kt)
#pragma unroll
    for (int t = 0; t < 4; ++t) {
      half4 hv;
#pragma unroll
      for (int j = 0; j < 4; ++j)
        hv[j] = (_Float16)W1g[(size_t)h*F_*F_ + (size_t)(16*kt + 4*q + j)*F_ + 16*t + ln];
      W1f[kt][t] = hv;
    }
  float b1r[4], gamt[4], bett[4];
#pragma unroll
  for (int t = 0; t < 4; ++t) {
    b1r[t]  = b1g[hoff + 16*t + ln];
    gamt[t] = ln_w[hoff + 16*t + ln];
    bett[t] = ln_b[hoff + 16*t + ln];
  }
  half4 maskA, maskI;
#pragma unroll
  for (int j = 0; j < 4; ++j) {
    maskA[j] = (_Float16)((4*q + j <= ln) ? 1.f : 0.f);
    maskI[j] = (_Float16)((4*q + j == ln) ? 1.f : 0.f);
  }
  const f32x4 zf4 = (f32x4){0.f, 0.f, 0.f, 0.f};

  const _Float16* S = isP ? V : Q;

  auto iter = [&](int i, Ck2& cur, Ck2& nxt) {
    half4 gzf[4];
    half4 xbTp[4];
    float co15p = 0.f;

    if (isP) {
      if (i < NC_) {
        co15p = cur.co15;
        if (i + 1 < NC_)
          load_ck2(nxt, Kp, S, coeff, brow + (size_t)(i+1)*K_, hoff, cobase, i+1, q, ln);
        f32x4 tgD[4];
#pragma unroll
        for (int t = 0; t < 4; ++t) {
          half4 dd = cur.xsA[t] - cur.xbA[t];
          tgD[t] = __builtin_amdgcn_mfma_f32_16x16x16f16(dd, maskI, zf4, 0, 0, 0);
          f32x4 x = __builtin_amdgcn_mfma_f32_16x16x16f16(cur.xbA[t], maskI, zf4, 0, 0, 0);
          half4 v;
#pragma unroll
          for (int r = 0; r < 4; ++r) v[r] = (_Float16)x[r];
          xbTp[t] = v;
        }
        f32x4 za[4];
#pragma unroll
        for (int t = 0; t < 4; ++t) {
          f32x4 zh = (f32x4){b1r[t], b1r[t], b1r[t], b1r[t]};
#pragma unroll
          for (int kt = 0; kt < 4; ++kt)
            zh = __builtin_amdgcn_mfma_f32_16x16x16f16(cur.xbA[kt], W1f[kt][t], zh, 0, 0, 0);
          za[t] = zh;
        }
#pragma unroll
        for (int r = 0; r < 4; ++r) {
          float zr[4], s1 = 0.f, s2 = 0.f;
#pragma unroll
          for (int t = 0; t < 4; ++t) { zr[t] = za[t][r]; s1 += zr[t]; s2 += zr[t]*zr[t]; }
          s1 = red16(s1); s2 = red16(s2);
          float mu = s1 * (1.f/F_);
          float istd = rsqrtf(s2 * (1.f/F_) - mu*mu + EPS_);
          float xh[4], gy[4], sg = 0.f, sx = 0.f;
#pragma unroll
          for (int t = 0; t < 4; ++t) {
            xh[t] = (zr[t] - mu) * istd;
            gy[t] = (gamt[t]*xh[t] + bett[t] - tgD[t][r]) * gamt[t];
            sg += gy[t]; sx += gy[t]*xh[t];
          }
          sg = red16(sg); sx = red16(sx);
          const float sc = istd * (1.f/F_);
#pragma unroll
          for (int t = 0; t < 4; ++t)
            gzf[t][r] = (_Float16)((F_*gy[t] - sg - xh[t]*sx) * sc);
        }
#pragma unroll
        for (int t = 0; t < 4; ++t) gzs[i & 3][t][lane] = gzf[t];
      }
    } else {
      if (i < NC_)
        load_ck2(nxt, Kp, S, coeff, brow + (size_t)i*K_, hoff, cobase, i, q, ln);
    }

    __syncthreads();

    if (isP) {
      if (i < NC_) {
        f32x4 cum3[4];
#pragma unroll
        for (int t = 0; t < 4; ++t)
          cum3[t] = __builtin_amdgcn_mfma_f32_16x16x16f16(maskA, gzf[t], zf4, 0, 0, 0);
#pragma unroll
        for (int t = 0; t < 4; ++t) {
          float tmp = b1r[t] - co15p * cum3[t][3];
          b1r[t] = __shfl(tmp, 48 + ln, 64);
        }
#pragma unroll
        for (int mt = 0; mt < 4; ++mt)
#pragma unroll
          for (int t = 0; t < 4; ++t) {
            f32x4 d = __builtin_amdgcn_mfma_f32_16x16x16f16(xbTp[mt], gzf[t], zf4, 0, 0, 0);
            half4 dt;
#pragma unroll
            for (int r = 0; r < 4; ++r) dt[r] = (_Float16)(co15p * d[r]);
            W1f[mt][t] = W1f[mt][t] - dt;
          }
      }
    } else {
      if (i > 0) {
        const int jc = i - 1;
        const size_t rowbase = brow + (size_t)jc * K_;
        half4 gz[4];
#pragma unroll
        for (int t = 0; t < 4; ++t) gz[t] = gzs[jc & 3][t][lane];
        f32x4 xcsD[4]; half4 xbT[4];
#pragma unroll
        for (int t = 0; t < 4; ++t) {
          xcsD[t] = __builtin_amdgcn_mfma_f32_16x16x16f16(cur.xsA[t], maskI, zf4, 0, 0, 0);
          f32x4 x = __builtin_amdgcn_mfma_f32_16x16x16f16(cur.xbA[t], maskI, zf4, 0, 0, 0);
          half4 v;
#pragma unroll
          for (int r = 0; r < 4; ++r) v[r] = (_Float16)x[r];
          xbT[t] = v;
        }
        f32x4 at0 = zf4, at1 = zf4;
        at0 = __builtin_amdgcn_mfma_f32_16x16x16f16(cur.xbA[0], cur.xsA[0], at0, 0, 0, 0);
        at0 = __builtin_amdgcn_mfma_f32_16x16x16f16(cur.xbA[1], cur.xsA[1], at0, 0, 0, 0);
        at1 = __builtin_amdgcn_mfma_f32_16x16x16f16(cur.xbA[2], cur.xsA[2], at1, 0, 0, 0);
        at1 = __builtin_amdgcn_mfma_f32_16x16x16f16(cur.xbA[3], cur.xsA[3], at1, 0, 0, 0);
        f32x4 at = at0 + at1;
        half4 atf;
#pragma unroll
        for (int r = 0; r < 4; ++r) atf[r] = (_Float16)((4*q + r <= ln) ? at[r] : 0.f);
        f32x4 cum[4], ag[4];
#pragma unroll
        for (int t = 0; t < 4; ++t) {
          cum[t] = __builtin_amdgcn_mfma_f32_16x16x16f16(maskA, gz[t], zf4, 0, 0, 0);
          ag[t]  = __builtin_amdgcn_mfma_f32_16x16x16f16(atf,   gz[t], zf4, 0, 0, 0);
        }
        float zbf[4][4];
#pragma unroll
        for (int t = 0; t < 4; ++t) {
          f32x4 zh = zf4;
#pragma unroll
          for (int kt = 0; kt < 4; ++kt)
            zh = __builtin_amdgcn_mfma_f32_16x16x16f16(cur.xsA[kt], W1f[kt][t], zh, 0, 0, 0);
#pragma unroll
          for (int r = 0; r < 4; ++r)
            zbf[t][r] = zh[r] + b1r[t] - cur.co4[r]*(ag[t][r] + cum[t][r]);
        }
#pragma unroll
        for (int r = 0; r < 4; ++r) {
          float zr[4], s1 = 0.f, s2 = 0.f;
#pragma unroll
          for (int t = 0; t < 4; ++t) { zr[t] = zbf[t][r]; s1 += zr[t]; s2 += zr[t]*zr[t]; }
          s1 = red16(s1); s2 = red16(s2);
          float mu = s1 * (1.f/F_);
          float istd = rsqrtf(s2 * (1.f/F_) - mu*mu + EPS_);
#pragma unroll
          for (int t = 0; t < 4; ++t) {
            float ov = xcsD[t][r] + gamt[t]*((zr[t] - mu)*istd) + bett[t];
            OF[(rowbase + 4*q + r) * C_ + hoff + 16*t + ln] = (_Float16)ov;
          }
        }
#pragma unroll
        for (int t = 0; t < 4; ++t) {
          float tmp = b1r[t] - cur.co15 * cum[t][3];
          b1r[t] = __shfl(tmp, 48 + ln, 64);
        }
#pragma unroll
        for (int mt = 0; mt < 4; ++mt)
#pragma unroll
          for (int t = 0; t < 4; ++t) {
            f32x4 d = __builtin_amdgcn_mfma_f32_16x16x16f16(xbT[mt], gz[t], zf4, 0, 0, 0);
            half4 dt;
#pragma unroll
            for (int r = 0; r < 4; ++r) dt[r] = (_Float16)(cur.co15 * d[r]);
            W1f[mt][t] = W1f[mt][t] - dt;
          }
      }
    }
  };

  Ck2 cka, ckb;
  if (isP) load_ck2(cka, Kp, S, coeff, brow, hoff, cobase, 0, q, ln);

  for (int i = 0; i < NC_; i += 2) {
    iter(i,     cka, ckb);
    iter(i + 1, ckb, cka);
  }
  iter(NC_, cka, ckb);
}

extern "C" void kernel_launch(void* const* d_in, const int* in_sizes, int n_in,
                              void* d_out, int out_size, void* d_ws, size_t ws_size,
                              hipStream_t stream)
{
  const float* hid   = (const float*)d_in[0];
  const float* q_w   = (const float*)d_in[1];
  const float* k_w   = (const float*)d_in[2];
  const float* v_w   = (const float*)d_in[3];
  const float* o_w   = (const float*)d_in[4];
  const float* lin_w = (const float*)d_in[5];
  const float* lin_b = (const float*)d_in[6];
  const float* ln_w  = (const float*)d_in[7];
  const float* ln_b  = (const float*)d_in[8];
  const float* W1    = (const float*)d_in[9];
  const float* b1    = (const float*)d_in[10];
  float* out = (float*)d_out;

  const size_t BLC = (size_t)B_ * L_ * C_;
  const size_t CC  = (size_t)C_ * C_;
  _Float16* HF  = (_Float16*)d_ws;              // hid f16; later scan output
  _Float16* WF3 = HF + BLC;                     // fused [3C][C] weights (QKV) / o_w
  _Float16* KF  = WF3 + 3*CC;
  _Float16* VF  = KF + BLC;
  float*    CO  = (float*)(VF + BLC);
  _Float16* QF  = (_Float16*)d_out;             // Q f16 in d_out (dead before final GEMM)

  const int M = B_ * L_, Kd = C_;
  dim3 ggQKV(3 * C_ / BN3, M / BM3);            // 24 x 64
  dim3 ggO(C_ / BN3, M / BM3);                  // 8 x 64
  const int n8h = (int)(BLC / 8);
  const int n8w = (int)(CC / 8);

  cast_f16<<<(n8h+255)/256, 256, 0, stream>>>(hid, HF, n8h);
  cast_f16<<<(n8w+255)/256, 256, 0, stream>>>(q_w, WF3,        n8w);
  cast_f16<<<(n8w+255)/256, 256, 0, stream>>>(k_w, WF3 + CC,   n8w);
  cast_f16<<<(n8w+255)/256, 256, 0, stream>>>(v_w, WF3 + 2*CC, n8w);
  gemm_f16_v3<_Float16><<<ggQKV, 512, 0, stream>>>(HF, WF3, QF, KF, VF, Kd);
  ilr_kernel<<<M / 16, 256, 0, stream>>>(hid, lin_w, lin_b, CO);
  scan_kernel<<<B_ * NH_, 128, 0, stream>>>(QF, KF, VF, CO, W1, b1, ln_w, ln_b, HF);
  cast_f16<<<(n8w+255)/256, 256, 0, stream>>>(o_w, WF3, n8w);
  gemm_f16_v3<float><<<ggO, 512, 0, stream>>>(HF, WF3, out, out, out, Kd);
}